// Round 2
// baseline (471.593 us; speedup 1.0000x reference)
//
#include <hip/hip_runtime.h>
#include <math.h>

#define NN 12288
#define EE 196608
#define FIN 128
#define ZD 256
#define HD 384
#define AD 256
#define NG 8
#define ACH 32   // chunks per graph for adjnew/hout partials
#define GCH 16   // chunks per graph for g2 partials

// ---------------- init / setup ----------------

__global__ __launch_bounds__(256) void k_init(unsigned* deg_dst, unsigned* deg_src,
    unsigned long long* A2) {
  unsigned i = blockIdx.x * 256u + threadIdx.x;
  if (i < NN) { deg_dst[i] = 0u; deg_src[i] = 0u; }
  if (i == 0u) *A2 = 0ull;
}

__global__ __launch_bounds__(256) void k_wcat(const float* __restrict__ We, const float* __restrict__ be,
    const float* __restrict__ Wp, const float* __restrict__ bp,
    float* __restrict__ Wcat, float* __restrict__ bcat) {
  unsigned i = blockIdx.x * 256u + threadIdx.x;
  if (i < 256u*384u) {
    unsigned k = i / 384u, j = i % 384u;
    Wcat[i] = (j < 128u) ? We[k*128u + j] : Wp[k*256u + (j - 128u)];
  }
  if (i < 384u) bcat[i] = (i < 128u) ? be[i] : bp[i - 128u];
}

// graph ranges: batch is sorted, binary-search the boundaries
__global__ __launch_bounds__(64) void k_gstart(const int* __restrict__ batch, int* __restrict__ gstart) {
  int g = threadIdx.x;
  if (g > NG) return;
  int lo = 0, hi = NN;
  while (lo < hi) { int mid = (lo + hi) >> 1; if (batch[mid] < g) lo = mid + 1; else hi = mid; }
  gstart[g] = lo;
}

// ---------------- edge passes (counting sort by dst and by src) ----------------

__global__ __launch_bounds__(256) void k_edge1(const int* __restrict__ src, const int* __restrict__ dst,
    unsigned* deg_dst, unsigned* deg_src) {
  unsigned e = blockIdx.x * 256u + threadIdx.x;
  if (e >= EE) return;
  atomicAdd(&deg_dst[dst[e]], 1u);
  atomicAdd(&deg_src[src[e]], 1u);
}

__global__ __launch_bounds__(1024) void k_scan(const unsigned* __restrict__ deg,
    unsigned* __restrict__ off, unsigned* __restrict__ cur, int n) {
  __shared__ unsigned partial[1024];
  int t = threadIdx.x;
  int chunk = (n + 1023) >> 10;
  int s = t * chunk; if (s > n) s = n;
  int e = s + chunk; if (e > n) e = n;
  unsigned sum = 0;
  for (int i = s; i < e; i++) sum += deg[i];
  partial[t] = sum;
  __syncthreads();
  for (int d = 1; d < 1024; d <<= 1) {
    unsigned v = (t >= d) ? partial[t - d] : 0u;
    __syncthreads();
    partial[t] += v;
    __syncthreads();
  }
  unsigned run = (t > 0) ? partial[t - 1] : 0u;
  for (int i = s; i < e; i++) { off[i] = run; cur[i] = run; run += deg[i]; }
  if (t == 1023) off[n] = partial[1023];
}

__global__ __launch_bounds__(256) void k_edge2(const int* __restrict__ src, const int* __restrict__ dst,
    unsigned* cur_dst, unsigned* cur_src, int* __restrict__ ssrc, int* __restrict__ sdst) {
  unsigned e = blockIdx.x * 256u + threadIdx.x;
  if (e >= EE) return;
  int s = src[e], d = dst[e];
  unsigned p = atomicAdd(&cur_dst[d], 1u); ssrc[p] = s;
  unsigned q = atomicAdd(&cur_src[s], 1u); sdst[q] = d;
}

// ---------------- ||A||_F^2 via pairwise duplicate count within dst-runs ----------------
// ||A||^2 = #ordered pairs (i,j) of edges with (s_i,d_i)==(s_j,d_j). Edges sorted by dst,
// so count equal-src ordered pairs within each dst run (includes i==j -> baseline E).

__global__ __launch_bounds__(256) void k_dup(const unsigned* __restrict__ off_dst,
    const int* __restrict__ ssrc, unsigned long long* A2) {
  int node = blockIdx.x * 4 + (threadIdx.x >> 6);
  int lane = threadIdx.x & 63;
  unsigned b = off_dst[node], e = off_dst[node + 1];
  unsigned cnt = 0;
  for (unsigned i0 = b; i0 < e; i0 += 64) {
    int si = (i0 + lane < e) ? ssrc[i0 + lane] : -1;
    for (unsigned j = b; j < e; j++) {
      int sj = ssrc[j];
      cnt += (si == sj) ? 1u : 0u;
    }
  }
  unsigned long long c = cnt;
#pragma unroll
  for (int o = 32; o >= 1; o >>= 1) c += __shfl_xor(c, o, 64);
  if (lane == 0 && c) atomicAdd(A2, c);
}

// ---------------- aggregation: Z = [x | mean_agg] ----------------

__global__ __launch_bounds__(256) void k_agg(const float* __restrict__ x,
    const unsigned* __restrict__ off_dst, const int* __restrict__ ssrc, float* __restrict__ Z) {
  int node = blockIdx.x * 4 + (threadIdx.x >> 6);
  int lane = threadIdx.x & 63;
  const float2* x2 = (const float2*)x;
  unsigned b = off_dst[node], e = off_dst[node + 1];
  float ax = 0.f, ay = 0.f;
  for (unsigned k = b; k < e; k++) {
    int s = ssrc[k];
    float2 v = x2[(size_t)s * 64 + lane];
    ax += v.x; ay += v.y;
  }
  float inv = 1.f / fmaxf((float)(e - b), 1.f);
  float2* Z2 = (float2*)Z;
  Z2[(size_t)node * 128 + lane] = x2[(size_t)node * 64 + lane];
  float2 m; m.x = ax * inv; m.y = ay * inv;
  Z2[(size_t)node * 128 + 64 + lane] = m;
}

// ---------------- fused GEMM: H[N,384] = Z[N,256] @ Wcat[256,384] + bcat ----------------

__global__ __launch_bounds__(256) void k_gemm(const float* __restrict__ Z,
    const float* __restrict__ Wcat, const float* __restrict__ bcat, float* __restrict__ H) {
  __shared__ float As[16][68];
  __shared__ float Bs[16][68];
  int t = threadIdx.x;
  int tx = t & 15, ty = t >> 4;
  int m0 = ty * 4, n0 = tx * 4;
  int gm = blockIdx.y * 64, gn = blockIdx.x * 64;
  float acc[4][4] = {};
  for (int k0 = 0; k0 < 256; k0 += 16) {
#pragma unroll
    for (int i = 0; i < 4; i++) {
      int idx = t + i * 256;
      int am = idx >> 4, ak = idx & 15;
      As[ak][am] = Z[(size_t)(gm + am) * 256 + k0 + ak];
      int bk = idx >> 6, bn = idx & 63;
      Bs[bk][bn] = Wcat[(size_t)(k0 + bk) * 384 + gn + bn];
    }
    __syncthreads();
#pragma unroll
    for (int kk = 0; kk < 16; kk++) {
      float4 a = *(const float4*)&As[kk][m0];
      float4 bq = *(const float4*)&Bs[kk][n0];
      float av[4] = {a.x, a.y, a.z, a.w};
      float bv[4] = {bq.x, bq.y, bq.z, bq.w};
#pragma unroll
      for (int i = 0; i < 4; i++)
#pragma unroll
        for (int j = 0; j < 4; j++)
          acc[i][j] += av[i] * bv[j];
    }
    __syncthreads();
  }
  float4 bq = *(const float4*)&bcat[gn + n0];
  float bb[4] = {bq.x, bq.y, bq.z, bq.w};
#pragma unroll
  for (int i = 0; i < 4; i++) {
    float4 o;
    o.x = acc[i][0] + bb[0]; o.y = acc[i][1] + bb[1];
    o.z = acc[i][2] + bb[2]; o.w = acc[i][3] + bb[3];
    *(float4*)&H[(size_t)(gm + m0 + i) * 384 + gn + n0] = o;
  }
}

// ---------------- normalize + block softmax ----------------

__global__ __launch_bounds__(256) void k_norm(const float* __restrict__ H,
    const int* __restrict__ batch, float* __restrict__ embed, float* __restrict__ Rc) {
  int node = blockIdx.x * 4 + (threadIdx.x >> 6);
  int lane = threadIdx.x & 63;
  const float* hrow = H + (size_t)node * 384;
  float v0 = hrow[lane], v1 = hrow[64 + lane];
  float ss = v0 * v0 + v1 * v1;
#pragma unroll
  for (int o = 32; o >= 1; o >>= 1) ss += __shfl_xor(ss, o, 64);
  float inv = 1.f / fmaxf(sqrtf(ss), 1e-12f);
  embed[(size_t)node * 128 + lane] = v0 * inv;
  embed[(size_t)node * 128 + 64 + lane] = v1 * inv;
  float4 p = *(const float4*)(hrow + 128 + 4 * lane);
  float ss2 = p.x * p.x + p.y * p.y + p.z * p.z + p.w * p.w;
#pragma unroll
  for (int o = 32; o >= 1; o >>= 1) ss2 += __shfl_xor(ss2, o, 64);
  float inv2 = 1.f / fmaxf(sqrtf(ss2), 1e-12f);
  p.x *= inv2; p.y *= inv2; p.z *= inv2; p.w *= inv2;
  int g = batch[node];
  if ((lane >> 3) == g) {
    float m = fmaxf(fmaxf(p.x, p.y), fmaxf(p.z, p.w));
#pragma unroll
    for (int o = 1; o <= 4; o <<= 1) m = fmaxf(m, __shfl_xor(m, o, 64));
    float e0 = expf(p.x - m), e1 = expf(p.y - m), e2 = expf(p.z - m), e3 = expf(p.w - m);
    float sum = e0 + e1 + e2 + e3;
#pragma unroll
    for (int o = 1; o <= 4; o <<= 1) sum += __shfl_xor(sum, o, 64);
    float r = 1.f / sum;
    float4 q; q.x = e0 * r; q.y = e1 * r; q.z = e2 * r; q.w = e3 * r;
    *(float4*)&Rc[(size_t)node * 32 + 4 * (lane - g * 8)] = q;
  }
}

// ---------------- Ar[i,:] = sum over out-edges of R[dst,:] ----------------

__global__ __launch_bounds__(256) void k_ar(const float* __restrict__ Rc,
    const unsigned* __restrict__ off_src, const int* __restrict__ sdst,
    const int* __restrict__ batch, float* __restrict__ Ar) {
  int node = blockIdx.x * 4 + (threadIdx.x >> 6);
  int lane = threadIdx.x & 63;
  int lg = lane >> 3, li = lane & 7;
  unsigned b = off_src[node], e = off_src[node + 1];
  float4 acc = {0.f, 0.f, 0.f, 0.f};
  const float4* R4 = (const float4*)Rc;
  for (unsigned k = b; k < e; k++) {
    int d = sdst[k];
    int g = batch[d];
    if (lg == g) {
      float4 r = R4[(size_t)d * 8 + li];
      acc.x += r.x; acc.y += r.y; acc.z += r.z; acc.w += r.w;
    }
  }
  ((float4*)Ar)[(size_t)node * 64 + lane] = acc;
}

// ---------------- h partial: per (graph, chunk), tile 32c1 x 128f ----------------

__global__ __launch_bounds__(256) void k_houtB(const float* __restrict__ Rc,
    const float* __restrict__ embed, const int* __restrict__ gstart, float* __restrict__ part) {
  int g = blockIdx.x, ch = blockIdx.y;
  int s0 = gstart[g], e0 = gstart[g + 1];
  int per = (e0 - s0 + ACH - 1) / ACH;
  int i0 = s0 + ch * per;
  int i1 = i0 + per; if (i1 > e0) i1 = e0;
  int t = threadIdx.x;
  int f4 = t & 31, c1g = t >> 5;   // c1 = c1g*4 + j
  __shared__ float rcs[64][32];
  float4 acc[4] = {};
  const float4* E4 = (const float4*)embed;
  for (int ib = i0; ib < i1; ib += 64) {
    int cnt = i1 - ib; if (cnt > 64) cnt = 64;
    __syncthreads();
    const float4* s4 = (const float4*)(Rc + (size_t)ib * 32);
    for (int idx = t; idx < cnt * 8; idx += 256) ((float4*)rcs)[idx] = s4[idx];
    __syncthreads();
    for (int n = 0; n < cnt; n++) {
      float4 e4 = E4[(size_t)(ib + n) * 32 + f4];
      float4 r = *(const float4*)&rcs[n][c1g * 4];
      float rv[4] = {r.x, r.y, r.z, r.w};
#pragma unroll
      for (int j = 0; j < 4; j++) {
        acc[j].x += rv[j] * e4.x; acc[j].y += rv[j] * e4.y;
        acc[j].z += rv[j] * e4.z; acc[j].w += rv[j] * e4.w;
      }
    }
  }
  float* p = part + (size_t)(g * ACH + ch) * 4096;
#pragma unroll
  for (int j = 0; j < 4; j++)
    *(float4*)&p[(c1g * 4 + j) * 128 + f4 * 4] = acc[j];
}

__global__ __launch_bounds__(256) void k_hred(const float* __restrict__ part, float* __restrict__ outh) {
  int i = blockIdx.x * 256 + threadIdx.x;   // 0..32767
  int g = i >> 12, off = i & 4095;
  const float* base = part + (size_t)g * ACH * 4096 + off;
  float s = 0.f;
#pragma unroll
  for (int ch = 0; ch < ACH; ch++) s += base[(size_t)ch * 4096];
  outh[i] = s;
}

// ---------------- adj_new partial: per (graph, chunk), tile 32c1 x 256c2 ----------------

__global__ __launch_bounds__(256) void k_adjnewB(const float* __restrict__ Rc,
    const float* __restrict__ Ar, const int* __restrict__ gstart, float* __restrict__ part) {
  int g = blockIdx.x, ch = blockIdx.y;
  int s0 = gstart[g], e0 = gstart[g + 1];
  int per = (e0 - s0 + ACH - 1) / ACH;
  int i0 = s0 + ch * per;
  int i1 = i0 + per; if (i1 > e0) i1 = e0;
  int t = threadIdx.x;
  int c2q = t & 63, c1g = t >> 6;   // c1 = c1g*8 + j
  __shared__ float rcs[64][32];
  float4 acc[8] = {};
  const float4* Ar4 = (const float4*)Ar;
  for (int ib = i0; ib < i1; ib += 64) {
    int cnt = i1 - ib; if (cnt > 64) cnt = 64;
    __syncthreads();
    const float4* s4 = (const float4*)(Rc + (size_t)ib * 32);
    for (int idx = t; idx < cnt * 8; idx += 256) ((float4*)rcs)[idx] = s4[idx];
    __syncthreads();
    for (int n = 0; n < cnt; n++) {
      float4 a4 = Ar4[(size_t)(ib + n) * 64 + c2q];
      float4 r0 = *(const float4*)&rcs[n][c1g * 8];
      float4 r1 = *(const float4*)&rcs[n][c1g * 8 + 4];
      float rv[8] = {r0.x, r0.y, r0.z, r0.w, r1.x, r1.y, r1.z, r1.w};
#pragma unroll
      for (int j = 0; j < 8; j++) {
        acc[j].x += rv[j] * a4.x; acc[j].y += rv[j] * a4.y;
        acc[j].z += rv[j] * a4.z; acc[j].w += rv[j] * a4.w;
      }
    }
  }
  float* p = part + (size_t)(g * ACH + ch) * 8192;
#pragma unroll
  for (int j = 0; j < 8; j++)
    *(float4*)&p[(c1g * 8 + j) * 256 + c2q * 4] = acc[j];
}

__global__ __launch_bounds__(256) void k_adjred(const float* __restrict__ part, float* __restrict__ outa) {
  int i = blockIdx.x * 256 + threadIdx.x;   // 0..65535
  int g = i >> 13, off = i & 8191;
  const float* base = part + (size_t)g * ACH * 8192 + off;
  float s = 0.f;
#pragma unroll
  for (int ch = 0; ch < ACH; ch++) s += base[(size_t)ch * 8192];
  outa[i] = s;
}

// ---------------- G = R^T R partial (block-diag), for ||RR^T||_F^2 ----------------

__global__ __launch_bounds__(256) void k_g2B(const float* __restrict__ Rc,
    const int* __restrict__ gstart, float* __restrict__ Gpart) {
  int g = blockIdx.x, ch = blockIdx.y;
  int s0 = gstart[g], e0 = gstart[g + 1];
  int per = (e0 - s0 + GCH - 1) / GCH;
  int i0 = s0 + ch * per;
  int i1 = i0 + per; if (i1 > e0) i1 = e0;
  int t = threadIdx.x;
  int c2q = t & 7, c1 = t >> 3;
  __shared__ float rcs[128][32];
  float4 acc = {};
  for (int ib = i0; ib < i1; ib += 128) {
    int cnt = i1 - ib; if (cnt > 128) cnt = 128;
    __syncthreads();
    const float4* s4 = (const float4*)(Rc + (size_t)ib * 32);
    for (int idx = t; idx < cnt * 8; idx += 256) ((float4*)rcs)[idx] = s4[idx];
    __syncthreads();
    for (int n = 0; n < cnt; n++) {
      float4 r2 = *(const float4*)&rcs[n][c2q * 4];
      float r1 = rcs[n][c1];
      acc.x += r1 * r2.x; acc.y += r1 * r2.y; acc.z += r1 * r2.z; acc.w += r1 * r2.w;
    }
  }
  *(float4*)&Gpart[(size_t)(g * GCH + ch) * 1024 + c1 * 32 + c2q * 4] = acc;
}

__global__ __launch_bounds__(256) void k_gred(const float* __restrict__ Gpart, float* __restrict__ Gbuf) {
  int i = blockIdx.x * 256 + threadIdx.x;   // 0..8191
  int g = i >> 10, off = i & 1023;
  const float* base = Gpart + (size_t)g * GCH * 1024 + off;
  float s = 0.f;
#pragma unroll
  for (int ch = 0; ch < GCH; ch++) s += base[(size_t)ch * 1024];
  Gbuf[i] = s;
}

// ---------------- final losses ----------------

__global__ __launch_bounds__(64) void k_final(const float* __restrict__ Gbuf,
    const unsigned long long* __restrict__ A2, float* __restrict__ out) {
  int lane = threadIdx.x;
  double tr = 0.0;
  for (int c = lane; c < 256; c += 64) tr += (double)out[(size_t)c * 257];  // diag of adj_new
  double g2 = 0.0;
  for (int i = lane; i < 8192; i += 64) { double v = (double)Gbuf[i]; g2 += v * v; }
#pragma unroll
  for (int o = 32; o >= 1; o >>= 1) { tr += __shfl_xor(tr, o, 64); g2 += __shfl_xor(g2, o, 64); }
  if (lane == 0) {
    double val = (double)(*A2) - 2.0 * tr + g2;  // ||A - RR^T||_F^2
    if (val < 0.0) val = 0.0;
    out[98304] = (float)(sqrt(val) / ((double)NN * (double)NN));
    out[98305] = (float)((double)NN * log(32.0));
  }
}

// ---------------- launch ----------------

extern "C" void kernel_launch(void* const* d_in, const int* in_sizes, int n_in,
                              void* d_out, int out_size, void* d_ws, size_t ws_size,
                              hipStream_t stream) {
  const float* x = (const float*)d_in[0];
  const int* ei = (const int*)d_in[1];
  const int* src = ei;
  const int* dst = ei + EE;
  const int* batch = (const int*)d_in[2];
  const float* Wemb = (const float*)d_in[3];
  const float* bemb = (const float*)d_in[4];
  const float* Wpool = (const float*)d_in[5];
  const float* bpool = (const float*)d_in[6];
  float* out = (float*)d_out;

  char* w = (char*)d_ws;
  size_t off = 0;
  auto A = [&](size_t bytes) -> char* {
    char* p = w + off;
    off += (bytes + 255) & ~(size_t)255;
    return p;
  };
  unsigned* deg_dst = (unsigned*)A(NN * 4);
  unsigned* off_dst = (unsigned*)A((NN + 1) * 4);
  unsigned* cur_dst = (unsigned*)A(NN * 4);
  unsigned* deg_src = (unsigned*)A(NN * 4);
  unsigned* off_src = (unsigned*)A((NN + 1) * 4);
  unsigned* cur_src = (unsigned*)A(NN * 4);
  int* ssrc = (int*)A((size_t)EE * 4);
  int* sdst = (int*)A((size_t)EE * 4);
  int* gstart = (int*)A(64);
  float* Z = (float*)A((size_t)NN * ZD * 4);        // 12.6 MB; reused as part_adj (8 MB)
  float* H = (float*)A((size_t)NN * HD * 4);        // 18.9 MB; reused as part_h/Gpart/Gbuf
  float* embed = (float*)A((size_t)NN * FIN * 4);
  float* Rc = (float*)A((size_t)NN * 32 * 4);
  float* Ar = (float*)A((size_t)NN * AD * 4);
  float* Wcat = (float*)A(256 * 384 * 4);
  float* bcat = (float*)A(384 * 4);
  unsigned long long* A2 = (unsigned long long*)A(8);
  (void)ws_size; (void)in_sizes; (void)n_in; (void)out_size;  // ~54 MB

  // aliases into dead regions (Z dead after k_gemm; H dead after k_norm)
  float* part_adj = Z;                                   // 8 MB
  float* part_h = H;                                     // 4 MB
  float* Gpart  = (float*)((char*)H + 6u * 1024 * 1024); // 512 KB
  float* Gbuf   = (float*)((char*)H + 7u * 1024 * 1024); // 32 KB

  k_init<<<dim3(48), dim3(256), 0, stream>>>(deg_dst, deg_src, A2);
  k_wcat<<<dim3(384), dim3(256), 0, stream>>>(Wemb, bemb, Wpool, bpool, Wcat, bcat);
  k_gstart<<<dim3(1), dim3(64), 0, stream>>>(batch, gstart);
  k_edge1<<<dim3(EE / 256), dim3(256), 0, stream>>>(src, dst, deg_dst, deg_src);
  k_scan<<<dim3(1), dim3(1024), 0, stream>>>(deg_dst, off_dst, cur_dst, NN);
  k_scan<<<dim3(1), dim3(1024), 0, stream>>>(deg_src, off_src, cur_src, NN);
  k_edge2<<<dim3(EE / 256), dim3(256), 0, stream>>>(src, dst, cur_dst, cur_src, ssrc, sdst);
  k_dup<<<dim3(NN / 4), dim3(256), 0, stream>>>(off_dst, ssrc, A2);
  k_agg<<<dim3(NN / 4), dim3(256), 0, stream>>>(x, off_dst, ssrc, Z);
  k_gemm<<<dim3(6, 192), dim3(256), 0, stream>>>(Z, Wcat, bcat, H);
  k_norm<<<dim3(NN / 4), dim3(256), 0, stream>>>(H, batch, embed, Rc);
  k_ar<<<dim3(NN / 4), dim3(256), 0, stream>>>(Rc, off_src, sdst, batch, Ar);
  k_houtB<<<dim3(8, ACH), dim3(256), 0, stream>>>(Rc, embed, gstart, part_h);
  k_hred<<<dim3(128), dim3(256), 0, stream>>>(part_h, out + 65536);
  k_adjnewB<<<dim3(8, ACH), dim3(256), 0, stream>>>(Rc, Ar, gstart, part_adj);
  k_adjred<<<dim3(256), dim3(256), 0, stream>>>(part_adj, out);
  k_g2B<<<dim3(8, GCH), dim3(256), 0, stream>>>(Rc, gstart, Gpart);
  k_gred<<<dim3(32), dim3(256), 0, stream>>>(Gpart, Gbuf);
  k_final<<<dim3(1), dim3(64), 0, stream>>>(Gbuf, A2, out);
}

// Round 3
// 366.937 us; speedup vs baseline: 1.2852x; 1.2852x over previous
//
#include <hip/hip_runtime.h>
#include <math.h>

#define NN 12288
#define EE 196608
#define FIN 128
#define ZD 256
#define HD 384
#define AD 256
#define NG 8
#define ACH 32   // chunks per graph for adjnew/hout partials
#define GCH 16   // chunks per graph for g2 partials

// ---------------- init / setup ----------------

__global__ __launch_bounds__(256) void k_init(unsigned* deg_dst, unsigned* deg_src) {
  unsigned i = blockIdx.x * 256u + threadIdx.x;
  if (i < NN) { deg_dst[i] = 0u; deg_src[i] = 0u; }
}

__global__ __launch_bounds__(256) void k_wcat(const float* __restrict__ We, const float* __restrict__ be,
    const float* __restrict__ Wp, const float* __restrict__ bp,
    float* __restrict__ Wcat, float* __restrict__ bcat) {
  unsigned i = blockIdx.x * 256u + threadIdx.x;
  if (i < 256u*384u) {
    unsigned k = i / 384u, j = i % 384u;
    Wcat[i] = (j < 128u) ? We[k*128u + j] : Wp[k*256u + (j - 128u)];
  }
  if (i < 384u) bcat[i] = (i < 128u) ? be[i] : bp[i - 128u];
}

// graph ranges: batch is sorted, binary-search the boundaries
__global__ __launch_bounds__(64) void k_gstart(const int* __restrict__ batch, int* __restrict__ gstart) {
  int g = threadIdx.x;
  if (g > NG) return;
  int lo = 0, hi = NN;
  while (lo < hi) { int mid = (lo + hi) >> 1; if (batch[mid] < g) lo = mid + 1; else hi = mid; }
  gstart[g] = lo;
}

// ---------------- edge passes (counting sort by dst and by src) ----------------

__global__ __launch_bounds__(256) void k_edge1(const int* __restrict__ src, const int* __restrict__ dst,
    unsigned* deg_dst, unsigned* deg_src) {
  unsigned e = blockIdx.x * 256u + threadIdx.x;
  if (e >= EE) return;
  atomicAdd(&deg_dst[dst[e]], 1u);
  atomicAdd(&deg_src[src[e]], 1u);
}

__global__ __launch_bounds__(1024) void k_scan(const unsigned* __restrict__ deg,
    unsigned* __restrict__ off, unsigned* __restrict__ cur, int n) {
  __shared__ unsigned partial[1024];
  int t = threadIdx.x;
  int chunk = (n + 1023) >> 10;
  int s = t * chunk; if (s > n) s = n;
  int e = s + chunk; if (e > n) e = n;
  unsigned sum = 0;
  for (int i = s; i < e; i++) sum += deg[i];
  partial[t] = sum;
  __syncthreads();
  for (int d = 1; d < 1024; d <<= 1) {
    unsigned v = (t >= d) ? partial[t - d] : 0u;
    __syncthreads();
    partial[t] += v;
    __syncthreads();
  }
  unsigned run = (t > 0) ? partial[t - 1] : 0u;
  for (int i = s; i < e; i++) { off[i] = run; cur[i] = run; run += deg[i]; }
  if (t == 1023) off[n] = partial[1023];
}

__global__ __launch_bounds__(256) void k_edge2(const int* __restrict__ src, const int* __restrict__ dst,
    unsigned* cur_dst, unsigned* cur_src, int* __restrict__ ssrc, int* __restrict__ sdst) {
  unsigned e = blockIdx.x * 256u + threadIdx.x;
  if (e >= EE) return;
  int s = src[e], d = dst[e];
  unsigned p = atomicAdd(&cur_dst[d], 1u); ssrc[p] = s;
  unsigned q = atomicAdd(&cur_src[s], 1u); sdst[q] = d;
}

// ---------------- ||A||_F^2 via pairwise duplicate count within dst-runs ----------------
// ||A||^2 = #ordered pairs (i,j) of edges with (s_i,d_i)==(s_j,d_j). Edges sorted by dst,
// so count equal-src ordered pairs within each dst run (includes i==j -> baseline E).
// NOTE: no shared atomic — per-node partials, summed in k_final (same-address atomicAdd
// from 12k waves serialized at ~30cyc each = the 151us we just removed).

__global__ __launch_bounds__(256) void k_dup(const unsigned* __restrict__ off_dst,
    const int* __restrict__ ssrc, unsigned* __restrict__ dup_part) {
  int node = blockIdx.x * 4 + (threadIdx.x >> 6);
  int lane = threadIdx.x & 63;
  unsigned b = off_dst[node], e = off_dst[node + 1];
  unsigned cnt = 0;
  for (unsigned i0 = b; i0 < e; i0 += 64) {
    int si = (i0 + lane < e) ? ssrc[i0 + lane] : -1;
    for (unsigned j = b; j < e; j++) {
      int sj = ssrc[j];
      cnt += (si == sj) ? 1u : 0u;
    }
  }
#pragma unroll
  for (int o = 32; o >= 1; o >>= 1) cnt += __shfl_xor(cnt, o, 64);
  if (lane == 0) dup_part[node] = cnt;
}

// ---------------- aggregation: Z = [x | mean_agg] ----------------

__global__ __launch_bounds__(256) void k_agg(const float* __restrict__ x,
    const unsigned* __restrict__ off_dst, const int* __restrict__ ssrc, float* __restrict__ Z) {
  int node = blockIdx.x * 4 + (threadIdx.x >> 6);
  int lane = threadIdx.x & 63;
  const float2* x2 = (const float2*)x;
  unsigned b = off_dst[node], e = off_dst[node + 1];
  float ax = 0.f, ay = 0.f;
  for (unsigned k = b; k < e; k++) {
    int s = ssrc[k];
    float2 v = x2[(size_t)s * 64 + lane];
    ax += v.x; ay += v.y;
  }
  float inv = 1.f / fmaxf((float)(e - b), 1.f);
  float2* Z2 = (float2*)Z;
  Z2[(size_t)node * 128 + lane] = x2[(size_t)node * 64 + lane];
  float2 m; m.x = ax * inv; m.y = ay * inv;
  Z2[(size_t)node * 128 + 64 + lane] = m;
}

// ---------------- fused GEMM: H[N,384] = Z[N,256] @ Wcat[256,384] + bcat ----------------

__global__ __launch_bounds__(256) void k_gemm(const float* __restrict__ Z,
    const float* __restrict__ Wcat, const float* __restrict__ bcat, float* __restrict__ H) {
  __shared__ float As[16][68];
  __shared__ float Bs[16][68];
  int t = threadIdx.x;
  int tx = t & 15, ty = t >> 4;
  int m0 = ty * 4, n0 = tx * 4;
  int gm = blockIdx.y * 64, gn = blockIdx.x * 64;
  float acc[4][4] = {};
  for (int k0 = 0; k0 < 256; k0 += 16) {
#pragma unroll
    for (int i = 0; i < 4; i++) {
      int idx = t + i * 256;
      int am = idx >> 4, ak = idx & 15;
      As[ak][am] = Z[(size_t)(gm + am) * 256 + k0 + ak];
      int bk = idx >> 6, bn = idx & 63;
      Bs[bk][bn] = Wcat[(size_t)(k0 + bk) * 384 + gn + bn];
    }
    __syncthreads();
#pragma unroll
    for (int kk = 0; kk < 16; kk++) {
      float4 a = *(const float4*)&As[kk][m0];
      float4 bq = *(const float4*)&Bs[kk][n0];
      float av[4] = {a.x, a.y, a.z, a.w};
      float bv[4] = {bq.x, bq.y, bq.z, bq.w};
#pragma unroll
      for (int i = 0; i < 4; i++)
#pragma unroll
        for (int j = 0; j < 4; j++)
          acc[i][j] += av[i] * bv[j];
    }
    __syncthreads();
  }
  float4 bq = *(const float4*)&bcat[gn + n0];
  float bb[4] = {bq.x, bq.y, bq.z, bq.w};
#pragma unroll
  for (int i = 0; i < 4; i++) {
    float4 o;
    o.x = acc[i][0] + bb[0]; o.y = acc[i][1] + bb[1];
    o.z = acc[i][2] + bb[2]; o.w = acc[i][3] + bb[3];
    *(float4*)&H[(size_t)(gm + m0 + i) * 384 + gn + n0] = o;
  }
}

// ---------------- normalize + block softmax ----------------

__global__ __launch_bounds__(256) void k_norm(const float* __restrict__ H,
    const int* __restrict__ batch, float* __restrict__ embed, float* __restrict__ Rc) {
  int node = blockIdx.x * 4 + (threadIdx.x >> 6);
  int lane = threadIdx.x & 63;
  const float* hrow = H + (size_t)node * 384;
  float v0 = hrow[lane], v1 = hrow[64 + lane];
  float ss = v0 * v0 + v1 * v1;
#pragma unroll
  for (int o = 32; o >= 1; o >>= 1) ss += __shfl_xor(ss, o, 64);
  float inv = 1.f / fmaxf(sqrtf(ss), 1e-12f);
  embed[(size_t)node * 128 + lane] = v0 * inv;
  embed[(size_t)node * 128 + 64 + lane] = v1 * inv;
  float4 p = *(const float4*)(hrow + 128 + 4 * lane);
  float ss2 = p.x * p.x + p.y * p.y + p.z * p.z + p.w * p.w;
#pragma unroll
  for (int o = 32; o >= 1; o >>= 1) ss2 += __shfl_xor(ss2, o, 64);
  float inv2 = 1.f / fmaxf(sqrtf(ss2), 1e-12f);
  p.x *= inv2; p.y *= inv2; p.z *= inv2; p.w *= inv2;
  int g = batch[node];
  if ((lane >> 3) == g) {
    float m = fmaxf(fmaxf(p.x, p.y), fmaxf(p.z, p.w));
#pragma unroll
    for (int o = 1; o <= 4; o <<= 1) m = fmaxf(m, __shfl_xor(m, o, 64));
    float e0 = expf(p.x - m), e1 = expf(p.y - m), e2 = expf(p.z - m), e3 = expf(p.w - m);
    float sum = e0 + e1 + e2 + e3;
#pragma unroll
    for (int o = 1; o <= 4; o <<= 1) sum += __shfl_xor(sum, o, 64);
    float r = 1.f / sum;
    float4 q; q.x = e0 * r; q.y = e1 * r; q.z = e2 * r; q.w = e3 * r;
    *(float4*)&Rc[(size_t)node * 32 + 4 * (lane - g * 8)] = q;
  }
}

// ---------------- Ar[i,:] = sum over out-edges of R[dst,:] ----------------

__global__ __launch_bounds__(256) void k_ar(const float* __restrict__ Rc,
    const unsigned* __restrict__ off_src, const int* __restrict__ sdst,
    const int* __restrict__ batch, float* __restrict__ Ar) {
  int node = blockIdx.x * 4 + (threadIdx.x >> 6);
  int lane = threadIdx.x & 63;
  int lg = lane >> 3, li = lane & 7;
  unsigned b = off_src[node], e = off_src[node + 1];
  float4 acc = {0.f, 0.f, 0.f, 0.f};
  const float4* R4 = (const float4*)Rc;
  for (unsigned k = b; k < e; k++) {
    int d = sdst[k];
    int g = batch[d];
    if (lg == g) {
      float4 r = R4[(size_t)d * 8 + li];
      acc.x += r.x; acc.y += r.y; acc.z += r.z; acc.w += r.w;
    }
  }
  ((float4*)Ar)[(size_t)node * 64 + lane] = acc;
}

// ---------------- h partial: per (graph, chunk), tile 32c1 x 128f ----------------

__global__ __launch_bounds__(256) void k_houtB(const float* __restrict__ Rc,
    const float* __restrict__ embed, const int* __restrict__ gstart, float* __restrict__ part) {
  int g = blockIdx.x, ch = blockIdx.y;
  int s0 = gstart[g], e0 = gstart[g + 1];
  int per = (e0 - s0 + ACH - 1) / ACH;
  int i0 = s0 + ch * per;
  int i1 = i0 + per; if (i1 > e0) i1 = e0;
  int t = threadIdx.x;
  int f4 = t & 31, c1g = t >> 5;   // c1 = c1g*4 + j
  __shared__ float rcs[64][32];
  float4 acc[4] = {};
  const float4* E4 = (const float4*)embed;
  for (int ib = i0; ib < i1; ib += 64) {
    int cnt = i1 - ib; if (cnt > 64) cnt = 64;
    __syncthreads();
    const float4* s4 = (const float4*)(Rc + (size_t)ib * 32);
    for (int idx = t; idx < cnt * 8; idx += 256) ((float4*)rcs)[idx] = s4[idx];
    __syncthreads();
    for (int n = 0; n < cnt; n++) {
      float4 e4 = E4[(size_t)(ib + n) * 32 + f4];
      float4 r = *(const float4*)&rcs[n][c1g * 4];
      float rv[4] = {r.x, r.y, r.z, r.w};
#pragma unroll
      for (int j = 0; j < 4; j++) {
        acc[j].x += rv[j] * e4.x; acc[j].y += rv[j] * e4.y;
        acc[j].z += rv[j] * e4.z; acc[j].w += rv[j] * e4.w;
      }
    }
  }
  float* p = part + (size_t)(g * ACH + ch) * 4096;
#pragma unroll
  for (int j = 0; j < 4; j++)
    *(float4*)&p[(c1g * 4 + j) * 128 + f4 * 4] = acc[j];
}

__global__ __launch_bounds__(256) void k_hred(const float* __restrict__ part, float* __restrict__ outh) {
  int i = blockIdx.x * 256 + threadIdx.x;   // 0..32767
  int g = i >> 12, off = i & 4095;
  const float* base = part + (size_t)g * ACH * 4096 + off;
  float s = 0.f;
#pragma unroll
  for (int ch = 0; ch < ACH; ch++) s += base[(size_t)ch * 4096];
  outh[i] = s;
}

// ---------------- adj_new partial: per (graph, chunk), tile 32c1 x 256c2 ----------------

__global__ __launch_bounds__(256) void k_adjnewB(const float* __restrict__ Rc,
    const float* __restrict__ Ar, const int* __restrict__ gstart, float* __restrict__ part) {
  int g = blockIdx.x, ch = blockIdx.y;
  int s0 = gstart[g], e0 = gstart[g + 1];
  int per = (e0 - s0 + ACH - 1) / ACH;
  int i0 = s0 + ch * per;
  int i1 = i0 + per; if (i1 > e0) i1 = e0;
  int t = threadIdx.x;
  int c2q = t & 63, c1g = t >> 6;   // c1 = c1g*8 + j
  __shared__ float rcs[64][32];
  float4 acc[8] = {};
  const float4* Ar4 = (const float4*)Ar;
  for (int ib = i0; ib < i1; ib += 64) {
    int cnt = i1 - ib; if (cnt > 64) cnt = 64;
    __syncthreads();
    const float4* s4 = (const float4*)(Rc + (size_t)ib * 32);
    for (int idx = t; idx < cnt * 8; idx += 256) ((float4*)rcs)[idx] = s4[idx];
    __syncthreads();
    for (int n = 0; n < cnt; n++) {
      float4 a4 = Ar4[(size_t)(ib + n) * 64 + c2q];
      float4 r0 = *(const float4*)&rcs[n][c1g * 8];
      float4 r1 = *(const float4*)&rcs[n][c1g * 8 + 4];
      float rv[8] = {r0.x, r0.y, r0.z, r0.w, r1.x, r1.y, r1.z, r1.w};
#pragma unroll
      for (int j = 0; j < 8; j++) {
        acc[j].x += rv[j] * a4.x; acc[j].y += rv[j] * a4.y;
        acc[j].z += rv[j] * a4.z; acc[j].w += rv[j] * a4.w;
      }
    }
  }
  float* p = part + (size_t)(g * ACH + ch) * 8192;
#pragma unroll
  for (int j = 0; j < 8; j++)
    *(float4*)&p[(c1g * 8 + j) * 256 + c2q * 4] = acc[j];
}

__global__ __launch_bounds__(256) void k_adjred(const float* __restrict__ part, float* __restrict__ outa) {
  int i = blockIdx.x * 256 + threadIdx.x;   // 0..65535
  int g = i >> 13, off = i & 8191;
  const float* base = part + (size_t)g * ACH * 8192 + off;
  float s = 0.f;
#pragma unroll
  for (int ch = 0; ch < ACH; ch++) s += base[(size_t)ch * 8192];
  outa[i] = s;
}

// ---------------- G = R^T R partial (block-diag), for ||RR^T||_F^2 ----------------

__global__ __launch_bounds__(256) void k_g2B(const float* __restrict__ Rc,
    const int* __restrict__ gstart, float* __restrict__ Gpart) {
  int g = blockIdx.x, ch = blockIdx.y;
  int s0 = gstart[g], e0 = gstart[g + 1];
  int per = (e0 - s0 + GCH - 1) / GCH;
  int i0 = s0 + ch * per;
  int i1 = i0 + per; if (i1 > e0) i1 = e0;
  int t = threadIdx.x;
  int c2q = t & 7, c1 = t >> 3;
  __shared__ float rcs[128][32];
  float4 acc = {};
  for (int ib = i0; ib < i1; ib += 128) {
    int cnt = i1 - ib; if (cnt > 128) cnt = 128;
    __syncthreads();
    const float4* s4 = (const float4*)(Rc + (size_t)ib * 32);
    for (int idx = t; idx < cnt * 8; idx += 256) ((float4*)rcs)[idx] = s4[idx];
    __syncthreads();
    for (int n = 0; n < cnt; n++) {
      float4 r2 = *(const float4*)&rcs[n][c2q * 4];
      float r1 = rcs[n][c1];
      acc.x += r1 * r2.x; acc.y += r1 * r2.y; acc.z += r1 * r2.z; acc.w += r1 * r2.w;
    }
  }
  *(float4*)&Gpart[(size_t)(g * GCH + ch) * 1024 + c1 * 32 + c2q * 4] = acc;
}

__global__ __launch_bounds__(256) void k_gred(const float* __restrict__ Gpart, float* __restrict__ Gbuf) {
  int i = blockIdx.x * 256 + threadIdx.x;   // 0..8191
  int g = i >> 10, off = i & 1023;
  const float* base = Gpart + (size_t)g * GCH * 1024 + off;
  float s = 0.f;
#pragma unroll
  for (int ch = 0; ch < GCH; ch++) s += base[(size_t)ch * 1024];
  Gbuf[i] = s;
}

// ---------------- final losses ----------------

__global__ __launch_bounds__(64) void k_final(const float* __restrict__ Gbuf,
    const unsigned* __restrict__ dup_part, float* __restrict__ out) {
  int lane = threadIdx.x;
  double tr = 0.0;
  for (int c = lane; c < 256; c += 64) tr += (double)out[(size_t)c * 257];  // diag of adj_new
  double g2 = 0.0;
  for (int i = lane; i < 8192; i += 64) { double v = (double)Gbuf[i]; g2 += v * v; }
  unsigned long long a2 = 0ull;
  for (int i = lane; i < NN; i += 64) a2 += dup_part[i];
#pragma unroll
  for (int o = 32; o >= 1; o >>= 1) {
    tr += __shfl_xor(tr, o, 64); g2 += __shfl_xor(g2, o, 64); a2 += __shfl_xor(a2, o, 64);
  }
  if (lane == 0) {
    double val = (double)a2 - 2.0 * tr + g2;  // ||A - RR^T||_F^2
    if (val < 0.0) val = 0.0;
    out[98304] = (float)(sqrt(val) / ((double)NN * (double)NN));
    out[98305] = (float)((double)NN * log(32.0));
  }
}

// ---------------- launch ----------------

extern "C" void kernel_launch(void* const* d_in, const int* in_sizes, int n_in,
                              void* d_out, int out_size, void* d_ws, size_t ws_size,
                              hipStream_t stream) {
  const float* x = (const float*)d_in[0];
  const int* ei = (const int*)d_in[1];
  const int* src = ei;
  const int* dst = ei + EE;
  const int* batch = (const int*)d_in[2];
  const float* Wemb = (const float*)d_in[3];
  const float* bemb = (const float*)d_in[4];
  const float* Wpool = (const float*)d_in[5];
  const float* bpool = (const float*)d_in[6];
  float* out = (float*)d_out;

  char* w = (char*)d_ws;
  size_t off = 0;
  auto A = [&](size_t bytes) -> char* {
    char* p = w + off;
    off += (bytes + 255) & ~(size_t)255;
    return p;
  };
  unsigned* deg_dst = (unsigned*)A(NN * 4);
  unsigned* off_dst = (unsigned*)A((NN + 1) * 4);
  unsigned* cur_dst = (unsigned*)A(NN * 4);
  unsigned* deg_src = (unsigned*)A(NN * 4);
  unsigned* off_src = (unsigned*)A((NN + 1) * 4);
  unsigned* cur_src = (unsigned*)A(NN * 4);
  int* ssrc = (int*)A((size_t)EE * 4);
  int* sdst = (int*)A((size_t)EE * 4);
  int* gstart = (int*)A(64);
  unsigned* dup_part = (unsigned*)A(NN * 4);
  float* Z = (float*)A((size_t)NN * ZD * 4);        // 12.6 MB; reused as part_adj (8 MB)
  float* H = (float*)A((size_t)NN * HD * 4);        // 18.9 MB; reused as part_h/Gpart/Gbuf
  float* embed = (float*)A((size_t)NN * FIN * 4);
  float* Rc = (float*)A((size_t)NN * 32 * 4);
  float* Ar = (float*)A((size_t)NN * AD * 4);
  float* Wcat = (float*)A(256 * 384 * 4);
  float* bcat = (float*)A(384 * 4);
  (void)ws_size; (void)in_sizes; (void)n_in; (void)out_size;  // ~54 MB

  // aliases into dead regions (Z dead after k_gemm; H dead after k_norm)
  float* part_adj = Z;                                   // 8 MB
  float* part_h = H;                                     // 4 MB
  float* Gpart  = (float*)((char*)H + 6u * 1024 * 1024); // 512 KB
  float* Gbuf   = (float*)((char*)H + 7u * 1024 * 1024); // 32 KB

  k_init<<<dim3(48), dim3(256), 0, stream>>>(deg_dst, deg_src);
  k_wcat<<<dim3(384), dim3(256), 0, stream>>>(Wemb, bemb, Wpool, bpool, Wcat, bcat);
  k_gstart<<<dim3(1), dim3(64), 0, stream>>>(batch, gstart);
  k_edge1<<<dim3(EE / 256), dim3(256), 0, stream>>>(src, dst, deg_dst, deg_src);
  k_scan<<<dim3(1), dim3(1024), 0, stream>>>(deg_dst, off_dst, cur_dst, NN);
  k_scan<<<dim3(1), dim3(1024), 0, stream>>>(deg_src, off_src, cur_src, NN);
  k_edge2<<<dim3(EE / 256), dim3(256), 0, stream>>>(src, dst, cur_dst, cur_src, ssrc, sdst);
  k_dup<<<dim3(NN / 4), dim3(256), 0, stream>>>(off_dst, ssrc, dup_part);
  k_agg<<<dim3(NN / 4), dim3(256), 0, stream>>>(x, off_dst, ssrc, Z);
  k_gemm<<<dim3(6, 192), dim3(256), 0, stream>>>(Z, Wcat, bcat, H);
  k_norm<<<dim3(NN / 4), dim3(256), 0, stream>>>(H, batch, embed, Rc);
  k_ar<<<dim3(NN / 4), dim3(256), 0, stream>>>(Rc, off_src, sdst, batch, Ar);
  k_houtB<<<dim3(8, ACH), dim3(256), 0, stream>>>(Rc, embed, gstart, part_h);
  k_hred<<<dim3(128), dim3(256), 0, stream>>>(part_h, out + 65536);
  k_adjnewB<<<dim3(8, ACH), dim3(256), 0, stream>>>(Rc, Ar, gstart, part_adj);
  k_adjred<<<dim3(256), dim3(256), 0, stream>>>(part_adj, out);
  k_g2B<<<dim3(8, GCH), dim3(256), 0, stream>>>(Rc, gstart, Gpart);
  k_gred<<<dim3(32), dim3(256), 0, stream>>>(Gpart, Gbuf);
  k_final<<<dim3(1), dim3(64), 0, stream>>>(Gbuf, dup_part, out);
}

// Round 4
// 296.855 us; speedup vs baseline: 1.5886x; 1.2361x over previous
//
#include <hip/hip_runtime.h>
#include <math.h>

#define NN 12288
#define EE 196608
#define FIN 128
#define ZD 256
#define HD 384
#define AD 256
#define NG 8
#define ACH 32   // chunks per graph for adjnew/hout partials
#define GCH 16   // chunks per graph for g2 partials

// ---------------- init / setup ----------------

__global__ __launch_bounds__(256) void k_init(unsigned* deg_dst, unsigned* deg_src, double* acc) {
  unsigned i = blockIdx.x * 256u + threadIdx.x;
  if (i < NN) { deg_dst[i] = 0u; deg_src[i] = 0u; }
  if (i < 3u) acc[i] = 0.0;
}

__global__ __launch_bounds__(256) void k_wcat(const float* __restrict__ We, const float* __restrict__ be,
    const float* __restrict__ Wp, const float* __restrict__ bp,
    float* __restrict__ Wcat, float* __restrict__ bcat) {
  unsigned i = blockIdx.x * 256u + threadIdx.x;
  if (i < 256u*384u) {
    unsigned k = i / 384u, j = i % 384u;
    Wcat[i] = (j < 128u) ? We[k*128u + j] : Wp[k*256u + (j - 128u)];
  }
  if (i < 384u) bcat[i] = (i < 128u) ? be[i] : bp[i - 128u];
}

// graph ranges: batch is sorted, binary-search the boundaries
__global__ __launch_bounds__(64) void k_gstart(const int* __restrict__ batch, int* __restrict__ gstart) {
  int g = threadIdx.x;
  if (g > NG) return;
  int lo = 0, hi = NN;
  while (lo < hi) { int mid = (lo + hi) >> 1; if (batch[mid] < g) lo = mid + 1; else hi = mid; }
  gstart[g] = lo;
}

// ---------------- edge passes (counting sort by dst and by src) ----------------

__global__ __launch_bounds__(256) void k_edge1(const int* __restrict__ src, const int* __restrict__ dst,
    unsigned* deg_dst, unsigned* deg_src) {
  unsigned e = blockIdx.x * 256u + threadIdx.x;
  if (e >= EE) return;
  atomicAdd(&deg_dst[dst[e]], 1u);
  atomicAdd(&deg_src[src[e]], 1u);
}

__global__ __launch_bounds__(1024) void k_scan(const unsigned* __restrict__ deg,
    unsigned* __restrict__ off, unsigned* __restrict__ cur, int n) {
  __shared__ unsigned partial[1024];
  int t = threadIdx.x;
  int chunk = (n + 1023) >> 10;
  int s = t * chunk; if (s > n) s = n;
  int e = s + chunk; if (e > n) e = n;
  unsigned sum = 0;
  for (int i = s; i < e; i++) sum += deg[i];
  partial[t] = sum;
  __syncthreads();
  for (int d = 1; d < 1024; d <<= 1) {
    unsigned v = (t >= d) ? partial[t - d] : 0u;
    __syncthreads();
    partial[t] += v;
    __syncthreads();
  }
  unsigned run = (t > 0) ? partial[t - 1] : 0u;
  for (int i = s; i < e; i++) { off[i] = run; cur[i] = run; run += deg[i]; }
  if (t == 1023) off[n] = partial[1023];
}

__global__ __launch_bounds__(256) void k_edge2(const int* __restrict__ src, const int* __restrict__ dst,
    unsigned* cur_dst, unsigned* cur_src, int* __restrict__ ssrc, int* __restrict__ sdst) {
  unsigned e = blockIdx.x * 256u + threadIdx.x;
  if (e >= EE) return;
  int s = src[e], d = dst[e];
  unsigned p = atomicAdd(&cur_dst[d], 1u); ssrc[p] = s;
  unsigned q = atomicAdd(&cur_src[s], 1u); sdst[q] = d;
}

// ---------------- ||A||_F^2 via pairwise duplicate count within dst-runs ----------------

__global__ __launch_bounds__(256) void k_dup(const unsigned* __restrict__ off_dst,
    const int* __restrict__ ssrc, unsigned* __restrict__ dup_part) {
  int node = blockIdx.x * 4 + (threadIdx.x >> 6);
  int lane = threadIdx.x & 63;
  unsigned b = off_dst[node], e = off_dst[node + 1];
  unsigned cnt = 0;
  for (unsigned i0 = b; i0 < e; i0 += 64) {
    int si = (i0 + lane < e) ? ssrc[i0 + lane] : -1;
    for (unsigned j = b; j < e; j++) {
      int sj = ssrc[j];
      cnt += (si == sj) ? 1u : 0u;
    }
  }
#pragma unroll
  for (int o = 32; o >= 1; o >>= 1) cnt += __shfl_xor(cnt, o, 64);
  if (lane == 0) dup_part[node] = cnt;
}

// ---------------- aggregation: Z = [x | mean_agg] ----------------

__global__ __launch_bounds__(256) void k_agg(const float* __restrict__ x,
    const unsigned* __restrict__ off_dst, const int* __restrict__ ssrc, float* __restrict__ Z) {
  int node = blockIdx.x * 4 + (threadIdx.x >> 6);
  int lane = threadIdx.x & 63;
  const float2* x2 = (const float2*)x;
  unsigned b = off_dst[node], e = off_dst[node + 1];
  float ax = 0.f, ay = 0.f;
  for (unsigned k = b; k < e; k++) {
    int s = ssrc[k];
    float2 v = x2[(size_t)s * 64 + lane];
    ax += v.x; ay += v.y;
  }
  float inv = 1.f / fmaxf((float)(e - b), 1.f);
  float2* Z2 = (float2*)Z;
  Z2[(size_t)node * 128 + lane] = x2[(size_t)node * 64 + lane];
  float2 m; m.x = ax * inv; m.y = ay * inv;
  Z2[(size_t)node * 128 + 64 + lane] = m;
}

// ---------------- fused GEMM: H[N,384] = Z[N,256] @ Wcat[256,384] + bcat ----------------

__global__ __launch_bounds__(256) void k_gemm(const float* __restrict__ Z,
    const float* __restrict__ Wcat, const float* __restrict__ bcat, float* __restrict__ H) {
  __shared__ float As[16][68];
  __shared__ float Bs[16][68];
  int t = threadIdx.x;
  int tx = t & 15, ty = t >> 4;
  int m0 = ty * 4, n0 = tx * 4;
  int gm = blockIdx.y * 64, gn = blockIdx.x * 64;
  float acc[4][4] = {};
  for (int k0 = 0; k0 < 256; k0 += 16) {
#pragma unroll
    for (int i = 0; i < 4; i++) {
      int idx = t + i * 256;
      int am = idx >> 4, ak = idx & 15;
      As[ak][am] = Z[(size_t)(gm + am) * 256 + k0 + ak];
      int bk = idx >> 6, bn = idx & 63;
      Bs[bk][bn] = Wcat[(size_t)(k0 + bk) * 384 + gn + bn];
    }
    __syncthreads();
#pragma unroll
    for (int kk = 0; kk < 16; kk++) {
      float4 a = *(const float4*)&As[kk][m0];
      float4 bq = *(const float4*)&Bs[kk][n0];
      float av[4] = {a.x, a.y, a.z, a.w};
      float bv[4] = {bq.x, bq.y, bq.z, bq.w};
#pragma unroll
      for (int i = 0; i < 4; i++)
#pragma unroll
        for (int j = 0; j < 4; j++)
          acc[i][j] += av[i] * bv[j];
    }
    __syncthreads();
  }
  float4 bq = *(const float4*)&bcat[gn + n0];
  float bb[4] = {bq.x, bq.y, bq.z, bq.w};
#pragma unroll
  for (int i = 0; i < 4; i++) {
    float4 o;
    o.x = acc[i][0] + bb[0]; o.y = acc[i][1] + bb[1];
    o.z = acc[i][2] + bb[2]; o.w = acc[i][3] + bb[3];
    *(float4*)&H[(size_t)(gm + m0 + i) * 384 + gn + n0] = o;
  }
}

// ---------------- normalize + block softmax ----------------

__global__ __launch_bounds__(256) void k_norm(const float* __restrict__ H,
    const int* __restrict__ batch, float* __restrict__ embed, float* __restrict__ Rc) {
  int node = blockIdx.x * 4 + (threadIdx.x >> 6);
  int lane = threadIdx.x & 63;
  const float* hrow = H + (size_t)node * 384;
  float v0 = hrow[lane], v1 = hrow[64 + lane];
  float ss = v0 * v0 + v1 * v1;
#pragma unroll
  for (int o = 32; o >= 1; o >>= 1) ss += __shfl_xor(ss, o, 64);
  float inv = 1.f / fmaxf(sqrtf(ss), 1e-12f);
  embed[(size_t)node * 128 + lane] = v0 * inv;
  embed[(size_t)node * 128 + 64 + lane] = v1 * inv;
  float4 p = *(const float4*)(hrow + 128 + 4 * lane);
  float ss2 = p.x * p.x + p.y * p.y + p.z * p.z + p.w * p.w;
#pragma unroll
  for (int o = 32; o >= 1; o >>= 1) ss2 += __shfl_xor(ss2, o, 64);
  float inv2 = 1.f / fmaxf(sqrtf(ss2), 1e-12f);
  p.x *= inv2; p.y *= inv2; p.z *= inv2; p.w *= inv2;
  int g = batch[node];
  if ((lane >> 3) == g) {
    float m = fmaxf(fmaxf(p.x, p.y), fmaxf(p.z, p.w));
#pragma unroll
    for (int o = 1; o <= 4; o <<= 1) m = fmaxf(m, __shfl_xor(m, o, 64));
    float e0 = expf(p.x - m), e1 = expf(p.y - m), e2 = expf(p.z - m), e3 = expf(p.w - m);
    float sum = e0 + e1 + e2 + e3;
#pragma unroll
    for (int o = 1; o <= 4; o <<= 1) sum += __shfl_xor(sum, o, 64);
    float r = 1.f / sum;
    float4 q; q.x = e0 * r; q.y = e1 * r; q.z = e2 * r; q.w = e3 * r;
    *(float4*)&Rc[(size_t)node * 32 + 4 * (lane - g * 8)] = q;
  }
}

// ---------------- Ar[i,:] = sum over out-edges of R[dst,:] ----------------

__global__ __launch_bounds__(256) void k_ar(const float* __restrict__ Rc,
    const unsigned* __restrict__ off_src, const int* __restrict__ sdst,
    const int* __restrict__ batch, float* __restrict__ Ar) {
  int node = blockIdx.x * 4 + (threadIdx.x >> 6);
  int lane = threadIdx.x & 63;
  int lg = lane >> 3, li = lane & 7;
  unsigned b = off_src[node], e = off_src[node + 1];
  float4 acc = {0.f, 0.f, 0.f, 0.f};
  const float4* R4 = (const float4*)Rc;
  for (unsigned k = b; k < e; k++) {
    int d = sdst[k];
    int g = batch[d];
    if (lg == g) {
      float4 r = R4[(size_t)d * 8 + li];
      acc.x += r.x; acc.y += r.y; acc.z += r.z; acc.w += r.w;
    }
  }
  ((float4*)Ar)[(size_t)node * 64 + lane] = acc;
}

// ---------------- h partial: per (graph, chunk), tile 32c1 x 128f ----------------

__global__ __launch_bounds__(256) void k_houtB(const float* __restrict__ Rc,
    const float* __restrict__ embed, const int* __restrict__ gstart, float* __restrict__ part) {
  int g = blockIdx.x, ch = blockIdx.y;
  int s0 = gstart[g], e0 = gstart[g + 1];
  int per = (e0 - s0 + ACH - 1) / ACH;
  int i0 = s0 + ch * per;
  int i1 = i0 + per; if (i1 > e0) i1 = e0;
  int t = threadIdx.x;
  int f4 = t & 31, c1g = t >> 5;   // c1 = c1g*4 + j
  __shared__ float rcs[64][32];
  float4 acc[4] = {};
  const float4* E4 = (const float4*)embed;
  for (int ib = i0; ib < i1; ib += 64) {
    int cnt = i1 - ib; if (cnt > 64) cnt = 64;
    __syncthreads();
    const float4* s4 = (const float4*)(Rc + (size_t)ib * 32);
    for (int idx = t; idx < cnt * 8; idx += 256) ((float4*)rcs)[idx] = s4[idx];
    __syncthreads();
    for (int n = 0; n < cnt; n++) {
      float4 e4 = E4[(size_t)(ib + n) * 32 + f4];
      float4 r = *(const float4*)&rcs[n][c1g * 4];
      float rv[4] = {r.x, r.y, r.z, r.w};
#pragma unroll
      for (int j = 0; j < 4; j++) {
        acc[j].x += rv[j] * e4.x; acc[j].y += rv[j] * e4.y;
        acc[j].z += rv[j] * e4.z; acc[j].w += rv[j] * e4.w;
      }
    }
  }
  float* p = part + (size_t)(g * ACH + ch) * 4096;
#pragma unroll
  for (int j = 0; j < 4; j++)
    *(float4*)&p[(c1g * 4 + j) * 128 + f4 * 4] = acc[j];
}

__global__ __launch_bounds__(256) void k_hred(const float* __restrict__ part, float* __restrict__ outh) {
  int i = blockIdx.x * 256 + threadIdx.x;   // 0..32767
  int g = i >> 12, off = i & 4095;
  const float* base = part + (size_t)g * ACH * 4096 + off;
  float s = 0.f;
#pragma unroll
  for (int ch = 0; ch < ACH; ch++) s += base[(size_t)ch * 4096];
  outh[i] = s;
}

// ---------------- adj_new partial: per (graph, chunk), tile 32c1 x 256c2 ----------------

__global__ __launch_bounds__(256) void k_adjnewB(const float* __restrict__ Rc,
    const float* __restrict__ Ar, const int* __restrict__ gstart, float* __restrict__ part) {
  int g = blockIdx.x, ch = blockIdx.y;
  int s0 = gstart[g], e0 = gstart[g + 1];
  int per = (e0 - s0 + ACH - 1) / ACH;
  int i0 = s0 + ch * per;
  int i1 = i0 + per; if (i1 > e0) i1 = e0;
  int t = threadIdx.x;
  int c2q = t & 63, c1g = t >> 6;   // c1 = c1g*8 + j
  __shared__ float rcs[64][32];
  float4 acc[8] = {};
  const float4* Ar4 = (const float4*)Ar;
  for (int ib = i0; ib < i1; ib += 64) {
    int cnt = i1 - ib; if (cnt > 64) cnt = 64;
    __syncthreads();
    const float4* s4 = (const float4*)(Rc + (size_t)ib * 32);
    for (int idx = t; idx < cnt * 8; idx += 256) ((float4*)rcs)[idx] = s4[idx];
    __syncthreads();
    for (int n = 0; n < cnt; n++) {
      float4 a4 = Ar4[(size_t)(ib + n) * 64 + c2q];
      float4 r0 = *(const float4*)&rcs[n][c1g * 8];
      float4 r1 = *(const float4*)&rcs[n][c1g * 8 + 4];
      float rv[8] = {r0.x, r0.y, r0.z, r0.w, r1.x, r1.y, r1.z, r1.w};
#pragma unroll
      for (int j = 0; j < 8; j++) {
        acc[j].x += rv[j] * a4.x; acc[j].y += rv[j] * a4.y;
        acc[j].z += rv[j] * a4.z; acc[j].w += rv[j] * a4.w;
      }
    }
  }
  float* p = part + (size_t)(g * ACH + ch) * 8192;
#pragma unroll
  for (int j = 0; j < 8; j++)
    *(float4*)&p[(c1g * 8 + j) * 256 + c2q * 4] = acc[j];
}

__global__ __launch_bounds__(256) void k_adjred(const float* __restrict__ part, float* __restrict__ outa) {
  int i = blockIdx.x * 256 + threadIdx.x;   // 0..65535
  int g = i >> 13, off = i & 8191;
  const float* base = part + (size_t)g * ACH * 8192 + off;
  float s = 0.f;
#pragma unroll
  for (int ch = 0; ch < ACH; ch++) s += base[(size_t)ch * 8192];
  outa[i] = s;
}

// ---------------- G = R^T R partial (block-diag), for ||RR^T||_F^2 ----------------

__global__ __launch_bounds__(256) void k_g2B(const float* __restrict__ Rc,
    const int* __restrict__ gstart, float* __restrict__ Gpart) {
  int g = blockIdx.x, ch = blockIdx.y;
  int s0 = gstart[g], e0 = gstart[g + 1];
  int per = (e0 - s0 + GCH - 1) / GCH;
  int i0 = s0 + ch * per;
  int i1 = i0 + per; if (i1 > e0) i1 = e0;
  int t = threadIdx.x;
  int c2q = t & 7, c1 = t >> 3;
  __shared__ float rcs[128][32];
  float4 acc = {};
  for (int ib = i0; ib < i1; ib += 128) {
    int cnt = i1 - ib; if (cnt > 128) cnt = 128;
    __syncthreads();
    const float4* s4 = (const float4*)(Rc + (size_t)ib * 32);
    for (int idx = t; idx < cnt * 8; idx += 256) ((float4*)rcs)[idx] = s4[idx];
    __syncthreads();
    for (int n = 0; n < cnt; n++) {
      float4 r2 = *(const float4*)&rcs[n][c2q * 4];
      float r1 = rcs[n][c1];
      acc.x += r1 * r2.x; acc.y += r1 * r2.y; acc.z += r1 * r2.z; acc.w += r1 * r2.w;
    }
  }
  *(float4*)&Gpart[(size_t)(g * GCH + ch) * 1024 + c1 * 32 + c2q * 4] = acc;
}

__global__ __launch_bounds__(256) void k_gred(const float* __restrict__ Gpart, float* __restrict__ Gbuf) {
  int i = blockIdx.x * 256 + threadIdx.x;   // 0..8191
  int g = i >> 10, off = i & 1023;
  const float* base = Gpart + (size_t)g * GCH * 1024 + off;
  float s = 0.f;
#pragma unroll
  for (int ch = 0; ch < GCH; ch++) s += base[(size_t)ch * 1024];
  Gbuf[i] = s;
}

// ---------------- parallel loss reduction (replaces the 80us single-wave k_final) ----------------
// acc[0]=tr(adj_new), acc[1]=||G||^2, acc[2]=||A||^2

__global__ __launch_bounds__(256) void k_lossred(const float* __restrict__ Gbuf,
    const unsigned* __restrict__ dup_part, const float* __restrict__ outa,
    double* __restrict__ acc) {
  int tid = blockIdx.x * 256 + threadIdx.x;
  int stride = gridDim.x * 256;
  double tr = 0.0, g2 = 0.0, a2 = 0.0;
  for (int c = tid; c < 256; c += stride) tr += (double)outa[(size_t)c * 257];
  for (int i = tid; i < 8192; i += stride) { double v = (double)Gbuf[i]; g2 += v * v; }
  for (int i = tid; i < NN; i += stride) a2 += (double)dup_part[i];
#pragma unroll
  for (int o = 32; o >= 1; o >>= 1) {
    tr += __shfl_xor(tr, o, 64); g2 += __shfl_xor(g2, o, 64); a2 += __shfl_xor(a2, o, 64);
  }
  __shared__ double sm[3][4];
  int wid = threadIdx.x >> 6, lane = threadIdx.x & 63;
  if (lane == 0) { sm[0][wid] = tr; sm[1][wid] = g2; sm[2][wid] = a2; }
  __syncthreads();
  if (threadIdx.x == 0) {
    double t = 0, g = 0, a = 0;
    for (int wv = 0; wv < 4; wv++) { t += sm[0][wv]; g += sm[1][wv]; a += sm[2][wv]; }
    atomicAdd(&acc[0], t); atomicAdd(&acc[1], g); atomicAdd(&acc[2], a);
  }
}

__global__ __launch_bounds__(64) void k_final(const double* __restrict__ acc, float* __restrict__ out) {
  if (threadIdx.x == 0) {
    double val = acc[2] - 2.0 * acc[0] + acc[1];  // ||A - RR^T||_F^2
    if (val < 0.0) val = 0.0;
    out[98304] = (float)(sqrt(val) / ((double)NN * (double)NN));
    out[98305] = (float)((double)NN * log(32.0));
  }
}

// ---------------- launch ----------------

extern "C" void kernel_launch(void* const* d_in, const int* in_sizes, int n_in,
                              void* d_out, int out_size, void* d_ws, size_t ws_size,
                              hipStream_t stream) {
  const float* x = (const float*)d_in[0];
  const int* ei = (const int*)d_in[1];
  const int* src = ei;
  const int* dst = ei + EE;
  const int* batch = (const int*)d_in[2];
  const float* Wemb = (const float*)d_in[3];
  const float* bemb = (const float*)d_in[4];
  const float* Wpool = (const float*)d_in[5];
  const float* bpool = (const float*)d_in[6];
  float* out = (float*)d_out;

  char* w = (char*)d_ws;
  size_t off = 0;
  auto A = [&](size_t bytes) -> char* {
    char* p = w + off;
    off += (bytes + 255) & ~(size_t)255;
    return p;
  };
  unsigned* deg_dst = (unsigned*)A(NN * 4);
  unsigned* off_dst = (unsigned*)A((NN + 1) * 4);
  unsigned* cur_dst = (unsigned*)A(NN * 4);
  unsigned* deg_src = (unsigned*)A(NN * 4);
  unsigned* off_src = (unsigned*)A((NN + 1) * 4);
  unsigned* cur_src = (unsigned*)A(NN * 4);
  int* ssrc = (int*)A((size_t)EE * 4);
  int* sdst = (int*)A((size_t)EE * 4);
  int* gstart = (int*)A(64);
  unsigned* dup_part = (unsigned*)A(NN * 4);
  double* acc = (double*)A(3 * 8);
  float* Z = (float*)A((size_t)NN * ZD * 4);        // 12.6 MB; reused as part_adj (8 MB)
  float* H = (float*)A((size_t)NN * HD * 4);        // 18.9 MB; reused as part_h/Gpart/Gbuf
  float* embed = (float*)A((size_t)NN * FIN * 4);
  float* Rc = (float*)A((size_t)NN * 32 * 4);
  float* Ar = (float*)A((size_t)NN * AD * 4);
  float* Wcat = (float*)A(256 * 384 * 4);
  float* bcat = (float*)A(384 * 4);
  (void)ws_size; (void)in_sizes; (void)n_in; (void)out_size;  // ~54 MB

  // aliases into dead regions (Z dead after k_gemm; H dead after k_norm)
  float* part_adj = Z;                                   // 8 MB
  float* part_h = H;                                     // 4 MB
  float* Gpart  = (float*)((char*)H + 6u * 1024 * 1024); // 512 KB
  float* Gbuf   = (float*)((char*)H + 7u * 1024 * 1024); // 32 KB

  k_init<<<dim3(48), dim3(256), 0, stream>>>(deg_dst, deg_src, acc);
  k_wcat<<<dim3(384), dim3(256), 0, stream>>>(Wemb, bemb, Wpool, bpool, Wcat, bcat);
  k_gstart<<<dim3(1), dim3(64), 0, stream>>>(batch, gstart);
  k_edge1<<<dim3(EE / 256), dim3(256), 0, stream>>>(src, dst, deg_dst, deg_src);
  k_scan<<<dim3(1), dim3(1024), 0, stream>>>(deg_dst, off_dst, cur_dst, NN);
  k_scan<<<dim3(1), dim3(1024), 0, stream>>>(deg_src, off_src, cur_src, NN);
  k_edge2<<<dim3(EE / 256), dim3(256), 0, stream>>>(src, dst, cur_dst, cur_src, ssrc, sdst);
  k_dup<<<dim3(NN / 4), dim3(256), 0, stream>>>(off_dst, ssrc, dup_part);
  k_agg<<<dim3(NN / 4), dim3(256), 0, stream>>>(x, off_dst, ssrc, Z);
  k_gemm<<<dim3(6, 192), dim3(256), 0, stream>>>(Z, Wcat, bcat, H);
  k_norm<<<dim3(NN / 4), dim3(256), 0, stream>>>(H, batch, embed, Rc);
  k_ar<<<dim3(NN / 4), dim3(256), 0, stream>>>(Rc, off_src, sdst, batch, Ar);
  k_houtB<<<dim3(8, ACH), dim3(256), 0, stream>>>(Rc, embed, gstart, part_h);
  k_hred<<<dim3(128), dim3(256), 0, stream>>>(part_h, out + 65536);
  k_adjnewB<<<dim3(8, ACH), dim3(256), 0, stream>>>(Rc, Ar, gstart, part_adj);
  k_adjred<<<dim3(256), dim3(256), 0, stream>>>(part_adj, out);
  k_g2B<<<dim3(8, GCH), dim3(256), 0, stream>>>(Rc, gstart, Gpart);
  k_gred<<<dim3(32), dim3(256), 0, stream>>>(Gpart, Gbuf);
  k_lossred<<<dim3(64), dim3(256), 0, stream>>>(Gbuf, dup_part, out, acc);
  k_final<<<dim3(1), dim3(64), 0, stream>>>(acc, out);
}

// Round 5
// 269.799 us; speedup vs baseline: 1.7479x; 1.1003x over previous
//
#include <hip/hip_runtime.h>
#include <math.h>

#define NN 12288
#define EE 196608
#define FIN 128
#define HD 384
#define AD 256
#define NG 8
#define ACH 32   // chunks per graph for adjnew/hout partials
#define GCH 16   // chunks per graph for g2 partials

using short8 = __attribute__((ext_vector_type(8))) short;
using floatx4 = __attribute__((ext_vector_type(4))) float;

__device__ __forceinline__ unsigned short f2bf(float f) {
  union { float f; unsigned u; } v; v.f = f;
  unsigned r = v.u + 0x7FFFu + ((v.u >> 16) & 1u);   // round-to-nearest-even
  return (unsigned short)(r >> 16);
}

// ---------------- init / setup ----------------

__global__ __launch_bounds__(256) void k_init(unsigned* deg_dst, unsigned* deg_src, double* acc) {
  unsigned i = blockIdx.x * 256u + threadIdx.x;
  if (i < NN) { deg_dst[i] = 0u; deg_src[i] = 0u; }
  if (i < 3u) acc[i] = 0.0;
}

// WcatT[n][k] (bf16): n in [0,384) output col, k in [0,256); plus f32 bias
__global__ __launch_bounds__(256) void k_wcat(const float* __restrict__ We, const float* __restrict__ be,
    const float* __restrict__ Wp, const float* __restrict__ bp,
    unsigned short* __restrict__ WTb, float* __restrict__ bcat) {
  unsigned i = blockIdx.x * 256u + threadIdx.x;
  if (i < 384u * 256u) {
    unsigned n = i >> 8, k = i & 255u;
    float v = (n < 128u) ? We[k * 128u + n] : Wp[k * 256u + (n - 128u)];
    WTb[i] = f2bf(v);
  }
  if (i < 384u) bcat[i] = (i < 128u) ? be[i] : bp[i - 128u];
}

// graph ranges: batch is sorted, binary-search the boundaries
__global__ __launch_bounds__(64) void k_gstart(const int* __restrict__ batch, int* __restrict__ gstart) {
  int g = threadIdx.x;
  if (g > NG) return;
  int lo = 0, hi = NN;
  while (lo < hi) { int mid = (lo + hi) >> 1; if (batch[mid] < g) lo = mid + 1; else hi = mid; }
  gstart[g] = lo;
}

// ---------------- edge passes (counting sort by dst and by src) ----------------

__global__ __launch_bounds__(256) void k_edge1(const int* __restrict__ src, const int* __restrict__ dst,
    unsigned* deg_dst, unsigned* deg_src) {
  unsigned e = blockIdx.x * 256u + threadIdx.x;
  if (e >= EE) return;
  atomicAdd(&deg_dst[dst[e]], 1u);
  atomicAdd(&deg_src[src[e]], 1u);
}

__global__ __launch_bounds__(1024) void k_scan(const unsigned* __restrict__ deg,
    unsigned* __restrict__ off, unsigned* __restrict__ cur, int n) {
  __shared__ unsigned partial[1024];
  int t = threadIdx.x;
  int chunk = (n + 1023) >> 10;
  int s = t * chunk; if (s > n) s = n;
  int e = s + chunk; if (e > n) e = n;
  unsigned sum = 0;
  for (int i = s; i < e; i++) sum += deg[i];
  partial[t] = sum;
  __syncthreads();
  for (int d = 1; d < 1024; d <<= 1) {
    unsigned v = (t >= d) ? partial[t - d] : 0u;
    __syncthreads();
    partial[t] += v;
    __syncthreads();
  }
  unsigned run = (t > 0) ? partial[t - 1] : 0u;
  for (int i = s; i < e; i++) { off[i] = run; cur[i] = run; run += deg[i]; }
  if (t == 1023) off[n] = partial[1023];
}

__global__ __launch_bounds__(256) void k_edge2(const int* __restrict__ src, const int* __restrict__ dst,
    unsigned* cur_dst, unsigned* cur_src, int* __restrict__ ssrc, int* __restrict__ sdst) {
  unsigned e = blockIdx.x * 256u + threadIdx.x;
  if (e >= EE) return;
  int s = src[e], d = dst[e];
  unsigned p = atomicAdd(&cur_dst[d], 1u); ssrc[p] = s;
  unsigned q = atomicAdd(&cur_src[s], 1u); sdst[q] = d;
}

// ---------------- ||A||_F^2 via pairwise duplicate count within dst-runs ----------------

__global__ __launch_bounds__(256) void k_dup(const unsigned* __restrict__ off_dst,
    const int* __restrict__ ssrc, unsigned* __restrict__ dup_part) {
  int node = blockIdx.x * 4 + (threadIdx.x >> 6);
  int lane = threadIdx.x & 63;
  unsigned b = off_dst[node], e = off_dst[node + 1];
  unsigned cnt = 0;
  for (unsigned i0 = b; i0 < e; i0 += 64) {
    int si = (i0 + lane < e) ? ssrc[i0 + lane] : -1;
    for (unsigned j = b; j < e; j++) {
      int sj = ssrc[j];
      cnt += (si == sj) ? 1u : 0u;
    }
  }
#pragma unroll
  for (int o = 32; o >= 1; o >>= 1) cnt += __shfl_xor(cnt, o, 64);
  if (lane == 0) dup_part[node] = cnt;
}

// ---------------- aggregation: Zb = bf16([x | mean_agg]) ----------------

__global__ __launch_bounds__(256) void k_agg(const float* __restrict__ x,
    const unsigned* __restrict__ off_dst, const int* __restrict__ ssrc,
    unsigned short* __restrict__ Zb) {
  int node = blockIdx.x * 4 + (threadIdx.x >> 6);
  int lane = threadIdx.x & 63;
  const float2* x2 = (const float2*)x;
  unsigned b = off_dst[node], e = off_dst[node + 1];
  float ax = 0.f, ay = 0.f;
  for (unsigned k = b; k < e; k++) {
    int s = ssrc[k];
    float2 v = x2[(size_t)s * 64 + lane];
    ax += v.x; ay += v.y;
  }
  float inv = 1.f / fmaxf((float)(e - b), 1.f);
  float2 sv = x2[(size_t)node * 64 + lane];
  ushort2* Zb2 = (ushort2*)Zb;
  ushort2 a; a.x = f2bf(sv.x); a.y = f2bf(sv.y);
  ushort2 m; m.x = f2bf(ax * inv); m.y = f2bf(ay * inv);
  Zb2[(size_t)node * 128 + lane] = a;
  Zb2[(size_t)node * 128 + 64 + lane] = m;
}

// ---------------- MFMA GEMM: H[N,384] = Zb[N,256] @ WcatT^T + bcat ----------------
// 128x64 tile / block, 4 waves, mfma_f32_16x16x32_bf16.
// LDS holds A-chunk and full B panel in FRAGMENT order: every ds_read_b128 is
// lane*16 contiguous -> zero bank conflicts.

__global__ __launch_bounds__(256) void k_gemmM(const unsigned short* __restrict__ Zb,
    const unsigned short* __restrict__ WTb, const float* __restrict__ bcat,
    float* __restrict__ H) {
  __shared__ unsigned short Bl[64 * 256];   // 32 KB, frag order: [c][kc][lane][8]
  __shared__ unsigned short Al[128 * 32];   // 8 KB,  frag order: [strip][lane][8]
  int t = threadIdx.x;
  int gm = blockIdx.y * 128, gn = blockIdx.x * 64;

  // stage B once: 2048 pieces of 8 bf16
#pragma unroll
  for (int i = 0; i < 8; i++) {
    int p = t + i * 256;
    int n = p >> 5, pk = p & 31;
    int kc = pk >> 2, quad = pk & 3;
    uint4 v = *(const uint4*)&WTb[(size_t)(gn + n) * 256 + kc * 32 + quad * 8];
    *(uint4*)&Bl[(n >> 4) * 4096 + kc * 512 + ((n & 15) + 16 * quad) * 8] = v;
  }

  int w = t >> 6, l = t & 63;
  floatx4 acc[2][4] = {};

  for (int kc = 0; kc < 8; kc++) {
    __syncthreads();   // guards B staging (first iter) and Al reuse
#pragma unroll
    for (int i = 0; i < 2; i++) {
      int p = t + i * 256;
      int m = p >> 2, j = p & 3;
      uint4 v = *(const uint4*)&Zb[(size_t)(gm + m) * 256 + kc * 32 + j * 8];
      *(uint4*)&Al[(m >> 4) * 512 + ((m & 15) + 16 * j) * 8] = v;
    }
    __syncthreads();
    short8 a0 = *(const short8*)&Al[(2 * w) * 512 + l * 8];
    short8 a1 = *(const short8*)&Al[(2 * w + 1) * 512 + l * 8];
#pragma unroll
    for (int c = 0; c < 4; c++) {
      short8 b = *(const short8*)&Bl[c * 4096 + kc * 512 + l * 8];
      acc[0][c] = __builtin_amdgcn_mfma_f32_16x16x32_bf16(a0, b, acc[0][c], 0, 0, 0);
      acc[1][c] = __builtin_amdgcn_mfma_f32_16x16x32_bf16(a1, b, acc[1][c], 0, 0, 0);
    }
  }

  // epilogue: C/D layout col=lane&15, row=(lane>>4)*4+reg
  int col = l & 15, quad = l >> 4;
#pragma unroll
  for (int si = 0; si < 2; si++) {
    int m0 = gm + (2 * w + si) * 16 + quad * 4;
#pragma unroll
    for (int c = 0; c < 4; c++) {
      int n = gn + c * 16 + col;
      float bias = bcat[n];
#pragma unroll
      for (int r = 0; r < 4; r++)
        H[(size_t)(m0 + r) * 384 + n] = acc[si][c][r] + bias;
    }
  }
}

// ---------------- normalize + block softmax ----------------

__global__ __launch_bounds__(256) void k_norm(const float* __restrict__ H,
    const int* __restrict__ batch, float* __restrict__ embed, float* __restrict__ Rc) {
  int node = blockIdx.x * 4 + (threadIdx.x >> 6);
  int lane = threadIdx.x & 63;
  const float* hrow = H + (size_t)node * 384;
  float v0 = hrow[lane], v1 = hrow[64 + lane];
  float ss = v0 * v0 + v1 * v1;
#pragma unroll
  for (int o = 32; o >= 1; o >>= 1) ss += __shfl_xor(ss, o, 64);
  float inv = 1.f / fmaxf(sqrtf(ss), 1e-12f);
  embed[(size_t)node * 128 + lane] = v0 * inv;
  embed[(size_t)node * 128 + 64 + lane] = v1 * inv;
  float4 p = *(const float4*)(hrow + 128 + 4 * lane);
  float ss2 = p.x * p.x + p.y * p.y + p.z * p.z + p.w * p.w;
#pragma unroll
  for (int o = 32; o >= 1; o >>= 1) ss2 += __shfl_xor(ss2, o, 64);
  float inv2 = 1.f / fmaxf(sqrtf(ss2), 1e-12f);
  p.x *= inv2; p.y *= inv2; p.z *= inv2; p.w *= inv2;
  int g = batch[node];
  if ((lane >> 3) == g) {
    float m = fmaxf(fmaxf(p.x, p.y), fmaxf(p.z, p.w));
#pragma unroll
    for (int o = 1; o <= 4; o <<= 1) m = fmaxf(m, __shfl_xor(m, o, 64));
    float e0 = expf(p.x - m), e1 = expf(p.y - m), e2 = expf(p.z - m), e3 = expf(p.w - m);
    float sum = e0 + e1 + e2 + e3;
#pragma unroll
    for (int o = 1; o <= 4; o <<= 1) sum += __shfl_xor(sum, o, 64);
    float r = 1.f / sum;
    float4 q; q.x = e0 * r; q.y = e1 * r; q.z = e2 * r; q.w = e3 * r;
    *(float4*)&Rc[(size_t)node * 32 + 4 * (lane - g * 8)] = q;
  }
}

// ---------------- Ar[i,:] = sum over out-edges of R[dst,:] ----------------

__global__ __launch_bounds__(256) void k_ar(const float* __restrict__ Rc,
    const unsigned* __restrict__ off_src, const int* __restrict__ sdst,
    const int* __restrict__ batch, float* __restrict__ Ar) {
  int node = blockIdx.x * 4 + (threadIdx.x >> 6);
  int lane = threadIdx.x & 63;
  int lg = lane >> 3, li = lane & 7;
  unsigned b = off_src[node], e = off_src[node + 1];
  float4 acc = {0.f, 0.f, 0.f, 0.f};
  const float4* R4 = (const float4*)Rc;
  for (unsigned k = b; k < e; k++) {
    int d = sdst[k];
    int g = batch[d];
    if (lg == g) {
      float4 r = R4[(size_t)d * 8 + li];
      acc.x += r.x; acc.y += r.y; acc.z += r.z; acc.w += r.w;
    }
  }
  ((float4*)Ar)[(size_t)node * 64 + lane] = acc;
}

// ---------------- h partial: per (graph, chunk), tile 32c1 x 128f ----------------

__global__ __launch_bounds__(256) void k_houtB(const float* __restrict__ Rc,
    const float* __restrict__ embed, const int* __restrict__ gstart, float* __restrict__ part) {
  int g = blockIdx.x, ch = blockIdx.y;
  int s0 = gstart[g], e0 = gstart[g + 1];
  int per = (e0 - s0 + ACH - 1) / ACH;
  int i0 = s0 + ch * per;
  int i1 = i0 + per; if (i1 > e0) i1 = e0;
  int t = threadIdx.x;
  int f4 = t & 31, c1g = t >> 5;
  __shared__ float rcs[64][32];
  float4 acc[4] = {};
  const float4* E4 = (const float4*)embed;
  for (int ib = i0; ib < i1; ib += 64) {
    int cnt = i1 - ib; if (cnt > 64) cnt = 64;
    __syncthreads();
    const float4* s4 = (const float4*)(Rc + (size_t)ib * 32);
    for (int idx = t; idx < cnt * 8; idx += 256) ((float4*)rcs)[idx] = s4[idx];
    __syncthreads();
    for (int n = 0; n < cnt; n++) {
      float4 e4 = E4[(size_t)(ib + n) * 32 + f4];
      float4 r = *(const float4*)&rcs[n][c1g * 4];
      float rv[4] = {r.x, r.y, r.z, r.w};
#pragma unroll
      for (int j = 0; j < 4; j++) {
        acc[j].x += rv[j] * e4.x; acc[j].y += rv[j] * e4.y;
        acc[j].z += rv[j] * e4.z; acc[j].w += rv[j] * e4.w;
      }
    }
  }
  float* p = part + (size_t)(g * ACH + ch) * 4096;
#pragma unroll
  for (int j = 0; j < 4; j++)
    *(float4*)&p[(c1g * 4 + j) * 128 + f4 * 4] = acc[j];
}

__global__ __launch_bounds__(256) void k_hred(const float* __restrict__ part, float* __restrict__ outh) {
  int i = blockIdx.x * 256 + threadIdx.x;
  int g = i >> 12, off = i & 4095;
  const float* base = part + (size_t)g * ACH * 4096 + off;
  float s = 0.f;
#pragma unroll
  for (int ch = 0; ch < ACH; ch++) s += base[(size_t)ch * 4096];
  outh[i] = s;
}

// ---------------- adj_new partial: per (graph, chunk), tile 32c1 x 256c2 ----------------

__global__ __launch_bounds__(256) void k_adjnewB(const float* __restrict__ Rc,
    const float* __restrict__ Ar, const int* __restrict__ gstart, float* __restrict__ part) {
  int g = blockIdx.x, ch = blockIdx.y;
  int s0 = gstart[g], e0 = gstart[g + 1];
  int per = (e0 - s0 + ACH - 1) / ACH;
  int i0 = s0 + ch * per;
  int i1 = i0 + per; if (i1 > e0) i1 = e0;
  int t = threadIdx.x;
  int c2q = t & 63, c1g = t >> 6;
  __shared__ float rcs[64][32];
  float4 acc[8] = {};
  const float4* Ar4 = (const float4*)Ar;
  for (int ib = i0; ib < i1; ib += 64) {
    int cnt = i1 - ib; if (cnt > 64) cnt = 64;
    __syncthreads();
    const float4* s4 = (const float4*)(Rc + (size_t)ib * 32);
    for (int idx = t; idx < cnt * 8; idx += 256) ((float4*)rcs)[idx] = s4[idx];
    __syncthreads();
    for (int n = 0; n < cnt; n++) {
      float4 a4 = Ar4[(size_t)(ib + n) * 64 + c2q];
      float4 r0 = *(const float4*)&rcs[n][c1g * 8];
      float4 r1 = *(const float4*)&rcs[n][c1g * 8 + 4];
      float rv[8] = {r0.x, r0.y, r0.z, r0.w, r1.x, r1.y, r1.z, r1.w};
#pragma unroll
      for (int j = 0; j < 8; j++) {
        acc[j].x += rv[j] * a4.x; acc[j].y += rv[j] * a4.y;
        acc[j].z += rv[j] * a4.z; acc[j].w += rv[j] * a4.w;
      }
    }
  }
  float* p = part + (size_t)(g * ACH + ch) * 8192;
#pragma unroll
  for (int j = 0; j < 8; j++)
    *(float4*)&p[(c1g * 8 + j) * 256 + c2q * 4] = acc[j];
}

__global__ __launch_bounds__(256) void k_adjred(const float* __restrict__ part, float* __restrict__ outa) {
  int i = blockIdx.x * 256 + threadIdx.x;
  int g = i >> 13, off = i & 8191;
  const float* base = part + (size_t)g * ACH * 8192 + off;
  float s = 0.f;
#pragma unroll
  for (int ch = 0; ch < ACH; ch++) s += base[(size_t)ch * 8192];
  outa[i] = s;
}

// ---------------- G = R^T R partial (block-diag), for ||RR^T||_F^2 ----------------

__global__ __launch_bounds__(256) void k_g2B(const float* __restrict__ Rc,
    const int* __restrict__ gstart, float* __restrict__ Gpart) {
  int g = blockIdx.x, ch = blockIdx.y;
  int s0 = gstart[g], e0 = gstart[g + 1];
  int per = (e0 - s0 + GCH - 1) / GCH;
  int i0 = s0 + ch * per;
  int i1 = i0 + per; if (i1 > e0) i1 = e0;
  int t = threadIdx.x;
  int c2q = t & 7, c1 = t >> 3;
  __shared__ float rcs[128][32];
  float4 acc = {};
  for (int ib = i0; ib < i1; ib += 128) {
    int cnt = i1 - ib; if (cnt > 128) cnt = 128;
    __syncthreads();
    const float4* s4 = (const float4*)(Rc + (size_t)ib * 32);
    for (int idx = t; idx < cnt * 8; idx += 256) ((float4*)rcs)[idx] = s4[idx];
    __syncthreads();
    for (int n = 0; n < cnt; n++) {
      float4 r2 = *(const float4*)&rcs[n][c2q * 4];
      float r1 = rcs[n][c1];
      acc.x += r1 * r2.x; acc.y += r1 * r2.y; acc.z += r1 * r2.z; acc.w += r1 * r2.w;
    }
  }
  *(float4*)&Gpart[(size_t)(g * GCH + ch) * 1024 + c1 * 32 + c2q * 4] = acc;
}

__global__ __launch_bounds__(256) void k_gred(const float* __restrict__ Gpart, float* __restrict__ Gbuf) {
  int i = blockIdx.x * 256 + threadIdx.x;
  int g = i >> 10, off = i & 1023;
  const float* base = Gpart + (size_t)g * GCH * 1024 + off;
  float s = 0.f;
#pragma unroll
  for (int ch = 0; ch < GCH; ch++) s += base[(size_t)ch * 1024];
  Gbuf[i] = s;
}

// ---------------- parallel loss reduction ----------------
// acc[0]=tr(adj_new), acc[1]=||G||^2, acc[2]=||A||^2

__global__ __launch_bounds__(256) void k_lossred(const float* __restrict__ Gbuf,
    const unsigned* __restrict__ dup_part, const float* __restrict__ outa,
    double* __restrict__ acc) {
  int tid = blockIdx.x * 256 + threadIdx.x;
  int stride = gridDim.x * 256;
  double tr = 0.0, g2 = 0.0, a2 = 0.0;
  for (int c = tid; c < 256; c += stride) tr += (double)outa[(size_t)c * 257];
  for (int i = tid; i < 8192; i += stride) { double v = (double)Gbuf[i]; g2 += v * v; }
  for (int i = tid; i < NN; i += stride) a2 += (double)dup_part[i];
#pragma unroll
  for (int o = 32; o >= 1; o >>= 1) {
    tr += __shfl_xor(tr, o, 64); g2 += __shfl_xor(g2, o, 64); a2 += __shfl_xor(a2, o, 64);
  }
  __shared__ double sm[3][4];
  int wid = threadIdx.x >> 6, lane = threadIdx.x & 63;
  if (lane == 0) { sm[0][wid] = tr; sm[1][wid] = g2; sm[2][wid] = a2; }
  __syncthreads();
  if (threadIdx.x == 0) {
    double t = 0, g = 0, a = 0;
    for (int wv = 0; wv < 4; wv++) { t += sm[0][wv]; g += sm[1][wv]; a += sm[2][wv]; }
    atomicAdd(&acc[0], t); atomicAdd(&acc[1], g); atomicAdd(&acc[2], a);
  }
}

__global__ __launch_bounds__(64) void k_final(const double* __restrict__ acc, float* __restrict__ out) {
  if (threadIdx.x == 0) {
    double val = acc[2] - 2.0 * acc[0] + acc[1];
    if (val < 0.0) val = 0.0;
    out[98304] = (float)(sqrt(val) / ((double)NN * (double)NN));
    out[98305] = (float)((double)NN * log(32.0));
  }
}

// ---------------- launch ----------------

extern "C" void kernel_launch(void* const* d_in, const int* in_sizes, int n_in,
                              void* d_out, int out_size, void* d_ws, size_t ws_size,
                              hipStream_t stream) {
  const float* x = (const float*)d_in[0];
  const int* ei = (const int*)d_in[1];
  const int* src = ei;
  const int* dst = ei + EE;
  const int* batch = (const int*)d_in[2];
  const float* Wemb = (const float*)d_in[3];
  const float* bemb = (const float*)d_in[4];
  const float* Wpool = (const float*)d_in[5];
  const float* bpool = (const float*)d_in[6];
  float* out = (float*)d_out;

  char* w = (char*)d_ws;
  size_t off = 0;
  auto A = [&](size_t bytes) -> char* {
    char* p = w + off;
    off += (bytes + 255) & ~(size_t)255;
    return p;
  };
  unsigned* deg_dst = (unsigned*)A(NN * 4);
  unsigned* off_dst = (unsigned*)A((NN + 1) * 4);
  unsigned* cur_dst = (unsigned*)A(NN * 4);
  unsigned* deg_src = (unsigned*)A(NN * 4);
  unsigned* off_src = (unsigned*)A((NN + 1) * 4);
  unsigned* cur_src = (unsigned*)A(NN * 4);
  int* ssrc = (int*)A((size_t)EE * 4);
  int* sdst = (int*)A((size_t)EE * 4);
  int* gstart = (int*)A(64);
  unsigned* dup_part = (unsigned*)A(NN * 4);
  double* acc = (double*)A(3 * 8);
  unsigned short* Zb = (unsigned short*)A((size_t)NN * 256 * 2);  // 6.3 MB bf16
  float* H = (float*)A((size_t)NN * HD * 4);        // 18.9 MB; reused post-k_norm
  float* embed = (float*)A((size_t)NN * FIN * 4);
  float* Rc = (float*)A((size_t)NN * 32 * 4);
  float* Ar = (float*)A((size_t)NN * AD * 4);
  unsigned short* WTb = (unsigned short*)A(384 * 256 * 2);
  float* bcat = (float*)A(384 * 4);
  (void)ws_size; (void)in_sizes; (void)n_in; (void)out_size;  // ~48 MB

  // aliases into H (dead after k_norm): part_h 0..4MB, Gpart +6MB, Gbuf +7MB, part_adj +8..16MB
  float* part_h   = H;
  float* Gpart    = (float*)((char*)H + 6u * 1024 * 1024);
  float* Gbuf     = (float*)((char*)H + 7u * 1024 * 1024);
  float* part_adj = (float*)((char*)H + 8u * 1024 * 1024);

  k_init<<<dim3(48), dim3(256), 0, stream>>>(deg_dst, deg_src, acc);
  k_wcat<<<dim3(384), dim3(256), 0, stream>>>(Wemb, bemb, Wpool, bpool, WTb, bcat);
  k_gstart<<<dim3(1), dim3(64), 0, stream>>>(batch, gstart);
  k_edge1<<<dim3(EE / 256), dim3(256), 0, stream>>>(src, dst, deg_dst, deg_src);
  k_scan<<<dim3(1), dim3(1024), 0, stream>>>(deg_dst, off_dst, cur_dst, NN);
  k_scan<<<dim3(1), dim3(1024), 0, stream>>>(deg_src, off_src, cur_src, NN);
  k_edge2<<<dim3(EE / 256), dim3(256), 0, stream>>>(src, dst, cur_dst, cur_src, ssrc, sdst);
  k_dup<<<dim3(NN / 4), dim3(256), 0, stream>>>(off_dst, ssrc, dup_part);
  k_agg<<<dim3(NN / 4), dim3(256), 0, stream>>>(x, off_dst, ssrc, Zb);
  k_gemmM<<<dim3(6, 96), dim3(256), 0, stream>>>(Zb, WTb, bcat, H);
  k_norm<<<dim3(NN / 4), dim3(256), 0, stream>>>(H, batch, embed, Rc);
  k_ar<<<dim3(NN / 4), dim3(256), 0, stream>>>(Rc, off_src, sdst, batch, Ar);
  k_houtB<<<dim3(8, ACH), dim3(256), 0, stream>>>(Rc, embed, gstart, part_h);
  k_hred<<<dim3(128), dim3(256), 0, stream>>>(part_h, out + 65536);
  k_adjnewB<<<dim3(8, ACH), dim3(256), 0, stream>>>(Rc, Ar, gstart, part_adj);
  k_adjred<<<dim3(256), dim3(256), 0, stream>>>(part_adj, out);
  k_g2B<<<dim3(8, GCH), dim3(256), 0, stream>>>(Rc, gstart, Gpart);
  k_gred<<<dim3(32), dim3(256), 0, stream>>>(Gpart, Gbuf);
  k_lossred<<<dim3(64), dim3(256), 0, stream>>>(Gbuf, dup_part, out, acc);
  k_final<<<dim3(1), dim3(64), 0, stream>>>(acc, out);
}

// Round 6
// 225.923 us; speedup vs baseline: 2.0874x; 1.1942x over previous
//
#include <hip/hip_runtime.h>
#include <math.h>

#define NN 12288
#define EE 196608
#define FIN 128
#define HD 384
#define AD 256
#define NG 8
#define ACH 32   // chunks per graph for adjnew/hout partials
#define GCH 16   // chunks per graph for g2 partials

using short8 = __attribute__((ext_vector_type(8))) short;
using floatx4 = __attribute__((ext_vector_type(4))) float;

__device__ __forceinline__ unsigned short f2bf(float f) {
  union { float f; unsigned u; } v; v.f = f;
  unsigned r = v.u + 0x7FFFu + ((v.u >> 16) & 1u);   // round-to-nearest-even
  return (unsigned short)(r >> 16);
}

// ---------------- fused setup: weights, bias, deg/acc/done zero, gstart ----------------

__global__ __launch_bounds__(256) void k_setup(const float* __restrict__ We, const float* __restrict__ be,
    const float* __restrict__ Wp, const float* __restrict__ bp, const int* __restrict__ batch,
    unsigned* deg_dst, unsigned* deg_src, double* acc, unsigned* done,
    unsigned short* __restrict__ WTb, float* __restrict__ bcat, int* __restrict__ gstart) {
  unsigned i = blockIdx.x * 256u + threadIdx.x;
  if (i < 384u * 256u) {
    unsigned n = i >> 8, k = i & 255u;
    float v = (n < 128u) ? We[k * 128u + n] : Wp[k * 256u + (n - 128u)];
    WTb[i] = f2bf(v);
  }
  if (i < 384u) bcat[i] = (i < 128u) ? be[i] : bp[i - 128u];
  if (i < NN) { deg_dst[i] = 0u; deg_src[i] = 0u; }
  if (i < 3u) acc[i] = 0.0;
  if (i == 3u) *done = 0u;
  if (i <= NG) {   // batch sorted: binary-search graph boundaries
    int g = (int)i, lo = 0, hi = NN;
    while (lo < hi) { int mid = (lo + hi) >> 1; if (batch[mid] < g) lo = mid + 1; else hi = mid; }
    gstart[g] = lo;
  }
}

// ---------------- edge passes (counting sort by dst and by src) ----------------

__global__ __launch_bounds__(256) void k_edge1(const int* __restrict__ src, const int* __restrict__ dst,
    unsigned* deg_dst, unsigned* deg_src) {
  unsigned e = blockIdx.x * 256u + threadIdx.x;
  if (e >= EE) return;
  atomicAdd(&deg_dst[dst[e]], 1u);
  atomicAdd(&deg_src[src[e]], 1u);
}

// block 0 scans dst-degrees, block 1 scans src-degrees
__global__ __launch_bounds__(1024) void k_scan2(const unsigned* __restrict__ deg_dst,
    unsigned* __restrict__ off_dst, unsigned* __restrict__ cur_dst,
    const unsigned* __restrict__ deg_src, unsigned* __restrict__ off_src, unsigned* __restrict__ cur_src) {
  const unsigned* deg = blockIdx.x ? deg_src : deg_dst;
  unsigned* off = blockIdx.x ? off_src : off_dst;
  unsigned* cur = blockIdx.x ? cur_src : cur_dst;
  const int n = NN;
  __shared__ unsigned partial[1024];
  int t = threadIdx.x;
  int chunk = (n + 1023) >> 10;
  int s = t * chunk; if (s > n) s = n;
  int e = s + chunk; if (e > n) e = n;
  unsigned sum = 0;
  for (int i = s; i < e; i++) sum += deg[i];
  partial[t] = sum;
  __syncthreads();
  for (int d = 1; d < 1024; d <<= 1) {
    unsigned v = (t >= d) ? partial[t - d] : 0u;
    __syncthreads();
    partial[t] += v;
    __syncthreads();
  }
  unsigned run = (t > 0) ? partial[t - 1] : 0u;
  for (int i = s; i < e; i++) { off[i] = run; cur[i] = run; run += deg[i]; }
  if (t == 1023) off[n] = partial[1023];
}

__global__ __launch_bounds__(256) void k_edge2(const int* __restrict__ src, const int* __restrict__ dst,
    unsigned* cur_dst, unsigned* cur_src, int* __restrict__ ssrc, int* __restrict__ sdst) {
  unsigned e = blockIdx.x * 256u + threadIdx.x;
  if (e >= EE) return;
  int s = src[e], d = dst[e];
  unsigned p = atomicAdd(&cur_dst[d], 1u); ssrc[p] = s;
  unsigned q = atomicAdd(&cur_src[s], 1u); sdst[q] = d;
}

// ---------------- fused: dup-count (||A||^2) + mean aggregation -> Zb bf16 ----------------
// one wave per node; ssrc run stays hot in L1 across the two loops

__global__ __launch_bounds__(256) void k_dupagg(const float* __restrict__ x,
    const unsigned* __restrict__ off_dst, const int* __restrict__ ssrc,
    unsigned short* __restrict__ Zb, unsigned* __restrict__ dup_part) {
  int node = blockIdx.x * 4 + (threadIdx.x >> 6);
  int lane = threadIdx.x & 63;
  unsigned b = off_dst[node], e = off_dst[node + 1];
  // ||A||^2 contribution: ordered pairs with equal src within this dst run
  unsigned cnt = 0;
  for (unsigned i0 = b; i0 < e; i0 += 64) {
    int si = (i0 + lane < e) ? ssrc[i0 + lane] : -1;
    for (unsigned j = b; j < e; j++) {
      int sj = ssrc[j];
      cnt += (si == sj) ? 1u : 0u;
    }
  }
#pragma unroll
  for (int o = 32; o >= 1; o >>= 1) cnt += __shfl_xor(cnt, o, 64);
  if (lane == 0) dup_part[node] = cnt;
  // mean aggregation + self-concat, cast to bf16
  const float2* x2 = (const float2*)x;
  float ax = 0.f, ay = 0.f;
  for (unsigned k = b; k < e; k++) {
    int s = ssrc[k];
    float2 v = x2[(size_t)s * 64 + lane];
    ax += v.x; ay += v.y;
  }
  float inv = 1.f / fmaxf((float)(e - b), 1.f);
  float2 sv = x2[(size_t)node * 64 + lane];
  ushort2* Zb2 = (ushort2*)Zb;
  ushort2 a; a.x = f2bf(sv.x); a.y = f2bf(sv.y);
  ushort2 m; m.x = f2bf(ax * inv); m.y = f2bf(ay * inv);
  Zb2[(size_t)node * 128 + lane] = a;
  Zb2[(size_t)node * 128 + 64 + lane] = m;
}

// ---------------- MFMA GEMM: H[N,384] = Zb[N,256] @ WcatT^T + bcat ----------------

__global__ __launch_bounds__(256) void k_gemmM(const unsigned short* __restrict__ Zb,
    const unsigned short* __restrict__ WTb, const float* __restrict__ bcat,
    float* __restrict__ H) {
  __shared__ unsigned short Bl[64 * 256];   // 32 KB, frag order: [c][kc][lane][8]
  __shared__ unsigned short Al[128 * 32];   // 8 KB,  frag order: [strip][lane][8]
  int t = threadIdx.x;
  int gm = blockIdx.y * 128, gn = blockIdx.x * 64;

#pragma unroll
  for (int i = 0; i < 8; i++) {
    int p = t + i * 256;
    int n = p >> 5, pk = p & 31;
    int kc = pk >> 2, quad = pk & 3;
    uint4 v = *(const uint4*)&WTb[(size_t)(gn + n) * 256 + kc * 32 + quad * 8];
    *(uint4*)&Bl[(n >> 4) * 4096 + kc * 512 + ((n & 15) + 16 * quad) * 8] = v;
  }

  int w = t >> 6, l = t & 63;
  floatx4 acc[2][4] = {};

  for (int kc = 0; kc < 8; kc++) {
    __syncthreads();
#pragma unroll
    for (int i = 0; i < 2; i++) {
      int p = t + i * 256;
      int m = p >> 2, j = p & 3;
      uint4 v = *(const uint4*)&Zb[(size_t)(gm + m) * 256 + kc * 32 + j * 8];
      *(uint4*)&Al[(m >> 4) * 512 + ((m & 15) + 16 * j) * 8] = v;
    }
    __syncthreads();
    short8 a0 = *(const short8*)&Al[(2 * w) * 512 + l * 8];
    short8 a1 = *(const short8*)&Al[(2 * w + 1) * 512 + l * 8];
#pragma unroll
    for (int c = 0; c < 4; c++) {
      short8 b = *(const short8*)&Bl[c * 4096 + kc * 512 + l * 8];
      acc[0][c] = __builtin_amdgcn_mfma_f32_16x16x32_bf16(a0, b, acc[0][c], 0, 0, 0);
      acc[1][c] = __builtin_amdgcn_mfma_f32_16x16x32_bf16(a1, b, acc[1][c], 0, 0, 0);
    }
  }

  int col = l & 15, quad = l >> 4;
#pragma unroll
  for (int si = 0; si < 2; si++) {
    int m0 = gm + (2 * w + si) * 16 + quad * 4;
#pragma unroll
    for (int c = 0; c < 4; c++) {
      int n = gn + c * 16 + col;
      float bias = bcat[n];
#pragma unroll
      for (int r = 0; r < 4; r++)
        H[(size_t)(m0 + r) * 384 + n] = acc[si][c][r] + bias;
    }
  }
}

// ---------------- normalize + block softmax ----------------

__global__ __launch_bounds__(256) void k_norm(const float* __restrict__ H,
    const int* __restrict__ batch, float* __restrict__ embed, float* __restrict__ Rc) {
  int node = blockIdx.x * 4 + (threadIdx.x >> 6);
  int lane = threadIdx.x & 63;
  const float* hrow = H + (size_t)node * 384;
  float v0 = hrow[lane], v1 = hrow[64 + lane];
  float ss = v0 * v0 + v1 * v1;
#pragma unroll
  for (int o = 32; o >= 1; o >>= 1) ss += __shfl_xor(ss, o, 64);
  float inv = 1.f / fmaxf(sqrtf(ss), 1e-12f);
  embed[(size_t)node * 128 + lane] = v0 * inv;
  embed[(size_t)node * 128 + 64 + lane] = v1 * inv;
  float4 p = *(const float4*)(hrow + 128 + 4 * lane);
  float ss2 = p.x * p.x + p.y * p.y + p.z * p.z + p.w * p.w;
#pragma unroll
  for (int o = 32; o >= 1; o >>= 1) ss2 += __shfl_xor(ss2, o, 64);
  float inv2 = 1.f / fmaxf(sqrtf(ss2), 1e-12f);
  p.x *= inv2; p.y *= inv2; p.z *= inv2; p.w *= inv2;
  int g = batch[node];
  if ((lane >> 3) == g) {
    float m = fmaxf(fmaxf(p.x, p.y), fmaxf(p.z, p.w));
#pragma unroll
    for (int o = 1; o <= 4; o <<= 1) m = fmaxf(m, __shfl_xor(m, o, 64));
    float e0 = expf(p.x - m), e1 = expf(p.y - m), e2 = expf(p.z - m), e3 = expf(p.w - m);
    float sum = e0 + e1 + e2 + e3;
#pragma unroll
    for (int o = 1; o <= 4; o <<= 1) sum += __shfl_xor(sum, o, 64);
    float r = 1.f / sum;
    float4 q; q.x = e0 * r; q.y = e1 * r; q.z = e2 * r; q.w = e3 * r;
    *(float4*)&Rc[(size_t)node * 32 + 4 * (lane - g * 8)] = q;
  }
}

// ---------------- Ar[i,:] = sum over out-edges of R[dst,:] ----------------

__global__ __launch_bounds__(256) void k_ar(const float* __restrict__ Rc,
    const unsigned* __restrict__ off_src, const int* __restrict__ sdst,
    const int* __restrict__ batch, float* __restrict__ Ar) {
  int node = blockIdx.x * 4 + (threadIdx.x >> 6);
  int lane = threadIdx.x & 63;
  int lg = lane >> 3, li = lane & 7;
  unsigned b = off_src[node], e = off_src[node + 1];
  float4 acc = {0.f, 0.f, 0.f, 0.f};
  const float4* R4 = (const float4*)Rc;
  for (unsigned k = b; k < e; k++) {
    int d = sdst[k];
    int g = batch[d];
    if (lg == g) {
      float4 r = R4[(size_t)d * 8 + li];
      acc.x += r.x; acc.y += r.y; acc.z += r.z; acc.w += r.w;
    }
  }
  ((float4*)Ar)[(size_t)node * 64 + lane] = acc;
}

// ---------------- fused R^T-GEMM partials: role 0 = hout, 1 = adjnew, 2 = g2 ----------------

__global__ __launch_bounds__(256) void k_big3(const float* __restrict__ Rc,
    const float* __restrict__ embed, const float* __restrict__ Ar, const int* __restrict__ gstart,
    float* __restrict__ part_h, float* __restrict__ part_adj, float* __restrict__ Gpart) {
  int role = blockIdx.z;
  int g = blockIdx.x, ch = blockIdx.y;
  if (role == 2 && ch >= GCH) return;
  int s0 = gstart[g], e0 = gstart[g + 1];
  int nch = (role == 2) ? GCH : ACH;
  int per = (e0 - s0 + nch - 1) / nch;
  int i0 = s0 + ch * per;
  int i1 = i0 + per; if (i1 > e0) i1 = e0;
  int t = threadIdx.x;
  __shared__ float rcs[128][32];   // 16 KB; roles 0/1 use first 64 rows

  if (role == 0) {
    int f4 = t & 31, c1g = t >> 5;
    float4 acc[4] = {};
    const float4* E4 = (const float4*)embed;
    for (int ib = i0; ib < i1; ib += 64) {
      int cnt = i1 - ib; if (cnt > 64) cnt = 64;
      __syncthreads();
      const float4* s4 = (const float4*)(Rc + (size_t)ib * 32);
      for (int idx = t; idx < cnt * 8; idx += 256) ((float4*)rcs)[idx] = s4[idx];
      __syncthreads();
      for (int n = 0; n < cnt; n++) {
        float4 e4 = E4[(size_t)(ib + n) * 32 + f4];
        float4 r = *(const float4*)&rcs[n][c1g * 4];
        float rv[4] = {r.x, r.y, r.z, r.w};
#pragma unroll
        for (int j = 0; j < 4; j++) {
          acc[j].x += rv[j] * e4.x; acc[j].y += rv[j] * e4.y;
          acc[j].z += rv[j] * e4.z; acc[j].w += rv[j] * e4.w;
        }
      }
    }
    float* p = part_h + (size_t)(g * ACH + ch) * 4096;
#pragma unroll
    for (int j = 0; j < 4; j++)
      *(float4*)&p[(c1g * 4 + j) * 128 + f4 * 4] = acc[j];
  } else if (role == 1) {
    int c2q = t & 63, c1g = t >> 6;
    float4 acc[8] = {};
    const float4* Ar4 = (const float4*)Ar;
    for (int ib = i0; ib < i1; ib += 64) {
      int cnt = i1 - ib; if (cnt > 64) cnt = 64;
      __syncthreads();
      const float4* s4 = (const float4*)(Rc + (size_t)ib * 32);
      for (int idx = t; idx < cnt * 8; idx += 256) ((float4*)rcs)[idx] = s4[idx];
      __syncthreads();
      for (int n = 0; n < cnt; n++) {
        float4 a4 = Ar4[(size_t)(ib + n) * 64 + c2q];
        float4 r0 = *(const float4*)&rcs[n][c1g * 8];
        float4 r1 = *(const float4*)&rcs[n][c1g * 8 + 4];
        float rv[8] = {r0.x, r0.y, r0.z, r0.w, r1.x, r1.y, r1.z, r1.w};
#pragma unroll
        for (int j = 0; j < 8; j++) {
          acc[j].x += rv[j] * a4.x; acc[j].y += rv[j] * a4.y;
          acc[j].z += rv[j] * a4.z; acc[j].w += rv[j] * a4.w;
        }
      }
    }
    float* p = part_adj + (size_t)(g * ACH + ch) * 8192;
#pragma unroll
    for (int j = 0; j < 8; j++)
      *(float4*)&p[(c1g * 8 + j) * 256 + c2q * 4] = acc[j];
  } else {
    int c2q = t & 7, c1 = t >> 3;
    float4 acc = {};
    for (int ib = i0; ib < i1; ib += 128) {
      int cnt = i1 - ib; if (cnt > 128) cnt = 128;
      __syncthreads();
      const float4* s4 = (const float4*)(Rc + (size_t)ib * 32);
      for (int idx = t; idx < cnt * 8; idx += 256) ((float4*)rcs)[idx] = s4[idx];
      __syncthreads();
      for (int n = 0; n < cnt; n++) {
        float4 r2 = *(const float4*)&rcs[n][c2q * 4];
        float r1 = rcs[n][c1];
        acc.x += r1 * r2.x; acc.y += r1 * r2.y; acc.z += r1 * r2.z; acc.w += r1 * r2.w;
      }
    }
    *(float4*)&Gpart[(size_t)(g * GCH + ch) * 1024 + c1 * 32 + c2q * 4] = acc;
  }
}

// ---------------- fused reduce of all three partials ----------------
// i in [0,65536): adj_new; [65536,98304): h; [98304,106496): Gbuf

__global__ __launch_bounds__(256) void k_red3(const float* __restrict__ part_adj,
    const float* __restrict__ part_h, const float* __restrict__ Gpart,
    float* __restrict__ outa, float* __restrict__ outh, float* __restrict__ Gbuf) {
  int i = blockIdx.x * 256 + threadIdx.x;
  if (i < 65536) {
    int g = i >> 13, off = i & 8191;
    const float* base = part_adj + (size_t)g * ACH * 8192 + off;
    float s = 0.f;
#pragma unroll
    for (int ch = 0; ch < ACH; ch++) s += base[(size_t)ch * 8192];
    outa[i] = s;
  } else if (i < 98304) {
    int j = i - 65536;
    int g = j >> 12, off = j & 4095;
    const float* base = part_h + (size_t)g * ACH * 4096 + off;
    float s = 0.f;
#pragma unroll
    for (int ch = 0; ch < ACH; ch++) s += base[(size_t)ch * 4096];
    outh[j] = s;
  } else {
    int j = i - 98304;
    int g = j >> 10, off = j & 1023;
    const float* base = Gpart + (size_t)g * GCH * 1024 + off;
    float s = 0.f;
#pragma unroll
    for (int ch = 0; ch < GCH; ch++) s += base[(size_t)ch * 1024];
    Gbuf[j] = s;
  }
}

// ---------------- loss reduction + final (last-block pattern) ----------------
// acc[0]=tr(adj_new), acc[1]=||G||^2, acc[2]=||A||^2

__global__ __launch_bounds__(256) void k_lossfinal(const float* __restrict__ Gbuf,
    const unsigned* __restrict__ dup_part, const float* __restrict__ outa,
    double* __restrict__ acc, unsigned* __restrict__ done, float* __restrict__ out) {
  int tid = blockIdx.x * 256 + threadIdx.x;
  int stride = gridDim.x * 256;
  double tr = 0.0, g2 = 0.0, a2 = 0.0;
  for (int c = tid; c < 256; c += stride) tr += (double)outa[(size_t)c * 257];
  for (int i = tid; i < 8192; i += stride) { double v = (double)Gbuf[i]; g2 += v * v; }
  for (int i = tid; i < NN; i += stride) a2 += (double)dup_part[i];
#pragma unroll
  for (int o = 32; o >= 1; o >>= 1) {
    tr += __shfl_xor(tr, o, 64); g2 += __shfl_xor(g2, o, 64); a2 += __shfl_xor(a2, o, 64);
  }
  __shared__ double sm[3][4];
  int wid = threadIdx.x >> 6, lane = threadIdx.x & 63;
  if (lane == 0) { sm[0][wid] = tr; sm[1][wid] = g2; sm[2][wid] = a2; }
  __syncthreads();
  if (threadIdx.x == 0) {
    double t = 0, g = 0, a = 0;
    for (int wv = 0; wv < 4; wv++) { t += sm[0][wv]; g += sm[1][wv]; a += sm[2][wv]; }
    atomicAdd(&acc[0], t); atomicAdd(&acc[1], g); atomicAdd(&acc[2], a);
    __threadfence();
    unsigned prev = atomicAdd(done, 1u);
    if (prev == gridDim.x - 1) {   // last block: all acc contributions visible
      double trf = atomicAdd(&acc[0], 0.0);
      double g2f = atomicAdd(&acc[1], 0.0);
      double a2f = atomicAdd(&acc[2], 0.0);
      double val = a2f - 2.0 * trf + g2f;   // ||A - RR^T||_F^2
      if (val < 0.0) val = 0.0;
      out[98304] = (float)(sqrt(val) / ((double)NN * (double)NN));
      out[98305] = (float)((double)NN * log(32.0));
    }
  }
}

// ---------------- launch ----------------

extern "C" void kernel_launch(void* const* d_in, const int* in_sizes, int n_in,
                              void* d_out, int out_size, void* d_ws, size_t ws_size,
                              hipStream_t stream) {
  const float* x = (const float*)d_in[0];
  const int* ei = (const int*)d_in[1];
  const int* src = ei;
  const int* dst = ei + EE;
  const int* batch = (const int*)d_in[2];
  const float* Wemb = (const float*)d_in[3];
  const float* bemb = (const float*)d_in[4];
  const float* Wpool = (const float*)d_in[5];
  const float* bpool = (const float*)d_in[6];
  float* out = (float*)d_out;

  char* w = (char*)d_ws;
  size_t off = 0;
  auto A = [&](size_t bytes) -> char* {
    char* p = w + off;
    off += (bytes + 255) & ~(size_t)255;
    return p;
  };
  unsigned* deg_dst = (unsigned*)A(NN * 4);
  unsigned* off_dst = (unsigned*)A((NN + 1) * 4);
  unsigned* cur_dst = (unsigned*)A(NN * 4);
  unsigned* deg_src = (unsigned*)A(NN * 4);
  unsigned* off_src = (unsigned*)A((NN + 1) * 4);
  unsigned* cur_src = (unsigned*)A(NN * 4);
  int* ssrc = (int*)A((size_t)EE * 4);
  int* sdst = (int*)A((size_t)EE * 4);
  int* gstart = (int*)A(64);
  unsigned* dup_part = (unsigned*)A(NN * 4);
  double* acc = (double*)A(3 * 8);
  unsigned* done = (unsigned*)A(4);
  unsigned short* Zb = (unsigned short*)A((size_t)NN * 256 * 2);  // 6.3 MB bf16
  float* H = (float*)A((size_t)NN * HD * 4);        // 18.9 MB; reused post-k_norm
  float* embed = (float*)A((size_t)NN * FIN * 4);
  float* Rc = (float*)A((size_t)NN * 32 * 4);
  float* Ar = (float*)A((size_t)NN * AD * 4);
  unsigned short* WTb = (unsigned short*)A(384 * 256 * 2);
  float* bcat = (float*)A(384 * 4);
  (void)ws_size; (void)in_sizes; (void)n_in; (void)out_size;  // ~48 MB

  // aliases into H (dead after k_norm)
  float* part_h   = H;                                   // 4 MB
  float* Gpart    = (float*)((char*)H + 6u * 1024 * 1024); // 512 KB
  float* Gbuf     = (float*)((char*)H + 7u * 1024 * 1024); // 32 KB
  float* part_adj = (float*)((char*)H + 8u * 1024 * 1024); // 8 MB

  k_setup<<<dim3(384), dim3(256), 0, stream>>>(Wemb, bemb, Wpool, bpool, batch,
      deg_dst, deg_src, acc, done, WTb, bcat, gstart);
  k_edge1<<<dim3(EE / 256), dim3(256), 0, stream>>>(src, dst, deg_dst, deg_src);
  k_scan2<<<dim3(2), dim3(1024), 0, stream>>>(deg_dst, off_dst, cur_dst, deg_src, off_src, cur_src);
  k_edge2<<<dim3(EE / 256), dim3(256), 0, stream>>>(src, dst, cur_dst, cur_src, ssrc, sdst);
  k_dupagg<<<dim3(NN / 4), dim3(256), 0, stream>>>(x, off_dst, ssrc, Zb, dup_part);
  k_gemmM<<<dim3(6, 96), dim3(256), 0, stream>>>(Zb, WTb, bcat, H);
  k_norm<<<dim3(NN / 4), dim3(256), 0, stream>>>(H, batch, embed, Rc);
  k_ar<<<dim3(NN / 4), dim3(256), 0, stream>>>(Rc, off_src, sdst, batch, Ar);
  k_big3<<<dim3(8, ACH, 3), dim3(256), 0, stream>>>(Rc, embed, Ar, gstart, part_h, part_adj, Gpart);
  k_red3<<<dim3(416), dim3(256), 0, stream>>>(part_adj, part_h, Gpart, out, out + 65536, Gbuf);
  k_lossfinal<<<dim3(64), dim3(256), 0, stream>>>(Gbuf, dup_part, out, acc, done, out);
}